// Round 1
// baseline (7255.309 us; speedup 1.0000x reference)
//
#include <hip/hip_runtime.h>
#include <hip/hip_bf16.h>
#include <math.h>

// Problem constants
#define BB 4
#define SS 4096
#define DD 1024
#define GG 8
#define NN 64
#define KCONV 4
#define GDIM 128
#define BS (BB*SS)                    // 16384 rows
static const size_t BSD  = (size_t)BS * DD;      // 16,777,216
static const size_t BSGN = (size_t)BS * GG * NN; // 8,388,608

// ---------------------------------------------------------------------------
// K1: complex RMSNorm + magnitude.  One block per (b,s) row, 256 threads,
// float4 per thread (D=1024 = 256*4).
__global__ __launch_bounds__(256) void k_norm(
    const float* __restrict__ xr_in, const float* __restrict__ xi_in,
    const float* __restrict__ norm_w,
    float* __restrict__ xr_o, float* __restrict__ xi_o, float* __restrict__ mag_o)
{
    int row = blockIdx.x;
    int tid = threadIdx.x;
    size_t base = (size_t)row * DD;
    float4 vr = ((const float4*)(xr_in + base))[tid];
    float4 vi = ((const float4*)(xi_in + base))[tid];
    float ss = vr.x*vr.x + vr.y*vr.y + vr.z*vr.z + vr.w*vr.w
             + vi.x*vi.x + vi.y*vi.y + vi.z*vi.z + vi.w*vi.w;
    #pragma unroll
    for (int off = 32; off >= 1; off >>= 1) ss += __shfl_down(ss, off);
    __shared__ float ws4[4];
    if ((tid & 63) == 0) ws4[tid >> 6] = ss;
    __syncthreads();
    float tot = ws4[0] + ws4[1] + ws4[2] + ws4[3];
    float inv = rsqrtf(tot * (1.0f / DD) + 1e-6f);
    float4 w = ((const float4*)norm_w)[tid];
    vr.x *= inv * w.x; vr.y *= inv * w.y; vr.z *= inv * w.z; vr.w *= inv * w.w;
    vi.x *= inv * w.x; vi.y *= inv * w.y; vi.z *= inv * w.z; vi.w *= inv * w.w;
    float4 m;
    m.x = sqrtf(vr.x*vr.x + vi.x*vi.x + 1e-8f);
    m.y = sqrtf(vr.y*vr.y + vi.y*vi.y + 1e-8f);
    m.z = sqrtf(vr.z*vr.z + vi.z*vi.z + 1e-8f);
    m.w = sqrtf(vr.w*vr.w + vi.w*vi.w + 1e-8f);
    ((float4*)(xr_o + base))[tid] = vr;
    ((float4*)(xi_o + base))[tid] = vi;
    ((float4*)(mag_o + base))[tid] = m;
}

// ---------------------------------------------------------------------------
// K2: gate = sigmoid(mag @ Wg^T + bg).  M=16384, N=1024, K=1024.
// f32 tiled: BM=BN=64, BK=16, 256 thr, 4x4 per thread.
__global__ __launch_bounds__(256) void k_gate_gemm(
    const float* __restrict__ A, const float* __restrict__ W,
    const float* __restrict__ bg, float* __restrict__ out)
{
    __shared__ float As[16][64];
    __shared__ float Ws[16][64];
    int bm = blockIdx.y * 64, bn = blockIdx.x * 64;
    int tid = threadIdx.x;
    int tx = tid & 15, ty = tid >> 4;
    int lr = tid >> 2;            // 0..63
    int lk = (tid & 3) * 4;       // 0,4,8,12
    float acc[4][4] = {};
    for (int k0 = 0; k0 < DD; k0 += 16) {
        float4 a = *(const float4*)&A[(size_t)(bm + lr) * DD + k0 + lk];
        float4 w = *(const float4*)&W[(size_t)(bn + lr) * DD + k0 + lk];
        __syncthreads();
        As[lk+0][lr] = a.x; As[lk+1][lr] = a.y; As[lk+2][lr] = a.z; As[lk+3][lr] = a.w;
        Ws[lk+0][lr] = w.x; Ws[lk+1][lr] = w.y; Ws[lk+2][lr] = w.z; Ws[lk+3][lr] = w.w;
        __syncthreads();
        #pragma unroll
        for (int k = 0; k < 16; k++) {
            float av[4], wv[4];
            #pragma unroll
            for (int i = 0; i < 4; i++) { av[i] = As[k][ty + 16*i]; wv[i] = Ws[k][tx + 16*i]; }
            #pragma unroll
            for (int i = 0; i < 4; i++)
                #pragma unroll
                for (int j = 0; j < 4; j++)
                    acc[i][j] += av[i] * wv[j];
        }
    }
    #pragma unroll
    for (int i = 0; i < 4; i++) {
        int m = bm + ty + 16*i;
        #pragma unroll
        for (int j = 0; j < 4; j++) {
            int e = bn + tx + 16*j;
            float v = acc[i][j] + bg[e];
            out[(size_t)m * DD + e] = 1.0f / (1.0f + expf(-v));
        }
    }
}

// ---------------------------------------------------------------------------
// K3: rotate by theta and apply gate, in place.
__global__ __launch_bounds__(256) void k_rotate(
    float* __restrict__ xr, float* __restrict__ xi,
    const float* __restrict__ gate, const float* __restrict__ theta)
{
    size_t total = BSD;
    for (size_t idx = (size_t)blockIdx.x * blockDim.x + threadIdx.x;
         idx < total; idx += (size_t)gridDim.x * blockDim.x) {
        int d = (int)(idx & (DD - 1));
        float th = theta[d >> 3];
        float st, ct;
        sincosf(th, &st, &ct);
        float r = xr[idx], im = xi[idx], g = gate[idx];
        xr[idx] = g * (r * ct - im * st);
        xi[idx] = g * (r * st + im * ct);
    }
}

// ---------------------------------------------------------------------------
// K4: depthwise causal conv (K=4, 2-in 2-out channels per d) + activation.
__global__ __launch_bounds__(256) void k_conv(
    const float* __restrict__ xr, const float* __restrict__ xi,
    const float* __restrict__ cw, const float* __restrict__ cb,
    const float* __restrict__ act_thr,
    float* __restrict__ cxr, float* __restrict__ cxi)
{
    float ea = expf(act_thr[0]);
    size_t total = BSD;
    for (size_t idx = (size_t)blockIdx.x * blockDim.x + threadIdx.x;
         idx < total; idx += (size_t)gridDim.x * blockDim.x) {
        int d = (int)(idx & (DD - 1));
        size_t bs = idx >> 10;
        int s = (int)(bs & (SS - 1));
        float w0r[4], w0i[4], w1r[4], w1i[4];
        *(float4*)w0r = *(const float4*)&cw[(size_t)(2*d) * 8 + 0];
        *(float4*)w0i = *(const float4*)&cw[(size_t)(2*d) * 8 + 4];
        *(float4*)w1r = *(const float4*)&cw[(size_t)(2*d) * 8 + 8];
        *(float4*)w1i = *(const float4*)&cw[(size_t)(2*d) * 8 + 12];
        float cr = cb[2*d], ci = cb[2*d + 1];
        #pragma unroll
        for (int k = 0; k < 4; k++) {
            int sp = s - 3 + k;
            if (sp < 0) continue;
            size_t p = idx + ((size_t)(sp - s)) * DD;
            float vr = xr[p], vi = xi[p];
            cr += vr * w0r[k] + vi * w0i[k];
            ci += vr * w1r[k] + vi * w1i[k];
        }
        float act = 1.0f - expf(-(cr*cr + ci*ci) * ea);
        cxr[idx] = cr * act;
        cxi[idx] = ci * act;
    }
}

// ---------------------------------------------------------------------------
// K5: per (b,s): dt (clip-exp), a = a_mag*exp(i*ang), bx = (B@x)*dt_mag.
// 512 threads = 8 waves; wave g handles group g; lane n handles state n.
__global__ __launch_bounds__(512) void k_dtabx(
    const float* __restrict__ cxr, const float* __restrict__ cxi,
    const float* __restrict__ dtW, const float* __restrict__ dtb,
    const float* __restrict__ logA, const float* __restrict__ Aph,
    const float* __restrict__ BWr, const float* __restrict__ BWi,
    float* __restrict__ o_ar, float* __restrict__ o_ai,
    float* __restrict__ o_br, float* __restrict__ o_bi)
{
    int row = blockIdx.x;
    int tid = threadIdx.x;
    int g = tid >> 6, n = tid & 63;
    __shared__ float sr[DD];
    __shared__ float si[DD];
    size_t base = (size_t)row * DD;
    ((float2*)sr)[tid] = ((const float2*)(cxr + base))[tid];
    ((float2*)si)[tid] = ((const float2*)(cxi + base))[tid];
    __syncthreads();
    const float* xgr = sr + g * GDIM;
    const float* xgi = si + g * GDIM;
    // dt partial sums: lane n covers d = {n, n+64} of each 128-half
    float p0 = xgr[n]*dtW[n]       + xgr[n+64]*dtW[n+64]
             + xgi[n]*dtW[128+n]   + xgi[n+64]*dtW[192+n];
    float p1 = xgr[n]*dtW[256+n]   + xgr[n+64]*dtW[256+n+64]
             + xgi[n]*dtW[256+128+n] + xgi[n+64]*dtW[256+192+n];
    #pragma unroll
    for (int off = 32; off >= 1; off >>= 1) {
        p0 += __shfl_down(p0, off);
        p1 += __shfl_down(p1, off);
    }
    p0 = __shfl(p0, 0);
    p1 = __shfl(p1, 0);
    float dtm = fminf(fmaxf(expf(p0 + dtb[0]), 1e-4f), 2.0f);
    float dtp = fminf(fmaxf(expf(p1 + dtb[1]), 1e-4f), 2.0f);
    // a
    float la = logA[g * NN + n];
    float spl = log1pf(expf(la));
    float am = expf(-dtm * spl);
    float ang = dtp * Aph[g * NN + n];
    float sa, ca;
    sincosf(ang, &sa, &ca);
    // B projection
    const float* wr = BWr + (size_t)n * GDIM;
    const float* wi = BWi + (size_t)n * GDIM;
    float pr = 0.f, qi = 0.f, ur = 0.f, vi = 0.f;
    #pragma unroll 8
    for (int d = 0; d < GDIM; d++) {
        float xr = xgr[d], xi = xgi[d], wrd = wr[d], wid = wi[d];
        pr += xr * wrd; qi += xi * wid;
        ur += xr * wid; vi += xi * wrd;
    }
    size_t o = (size_t)row * (GG * NN) + tid;
    o_ar[o] = am * ca;
    o_ai[o] = am * sa;
    o_br[o] = (pr - qi) * dtm;
    o_bi[o] = (ur + vi) * dtm;
}

// ---------------------------------------------------------------------------
// K6: sequential complex scan over S, 2048 independent chains (b,g,n).
// 8-step load batching to keep multiple loads in flight.
__global__ __launch_bounds__(64) void k_scan(
    const float* __restrict__ ar, const float* __restrict__ ai,
    const float* __restrict__ br, const float* __restrict__ bi,
    float* __restrict__ Hr, float* __restrict__ Hi)
{
    int c = blockIdx.x * 64 + threadIdx.x;   // 0..2047
    int b = c >> 9;
    int gn = c & 511;
    size_t idx = (size_t)b * SS * 512 + gn;
    float hr = 0.f, hi = 0.f;
    for (int s0 = 0; s0 < SS; s0 += 8) {
        float va[8], vb[8], wr[8], wi[8];
        #pragma unroll
        for (int u = 0; u < 8; u++) {
            size_t p = idx + (size_t)u * 512;
            va[u] = ar[p]; vb[u] = ai[p]; wr[u] = br[p]; wi[u] = bi[p];
        }
        #pragma unroll
        for (int u = 0; u < 8; u++) {
            float nr = va[u]*hr - vb[u]*hi + wr[u];
            float ni = va[u]*hi + vb[u]*hr + wi[u];
            int s = s0 + u;
            if ((s & 255) == 255) {
                float hn = sqrtf(nr*nr + ni*ni + 1e-8f);
                float sc = fminf(hn, 100.0f) / hn;
                nr *= sc; ni *= sc;
            }
            size_t p = idx + (size_t)u * 512;
            Hr[p] = nr; Hi[p] = ni;
            hr = nr; hi = ni;
        }
        idx += 8 * 512;
    }
}

// ---------------------------------------------------------------------------
// K7: y = H @ C (complex), per (b,s,g) block of 128 threads (one per d').
__global__ __launch_bounds__(128) void k_cproj(
    const float* __restrict__ Hr, const float* __restrict__ Hi,
    const float* __restrict__ CWr, const float* __restrict__ CWi,
    float* __restrict__ yr, float* __restrict__ yi)
{
    int bid = blockIdx.x;       // row*8 + g
    int row = bid >> 3, g = bid & 7;
    int t = threadIdx.x;        // 0..127
    __shared__ float hr_s[NN];
    __shared__ float hi_s[NN];
    size_t hbase = (size_t)row * (GG * NN) + g * NN;
    if (t < 64) hr_s[t] = Hr[hbase + t];
    else        hi_s[t - 64] = Hi[hbase + t - 64];
    __syncthreads();
    const float* cr = CWr + (size_t)t * NN;
    const float* ci = CWi + (size_t)t * NN;
    float accr = 0.f, acci = 0.f;
    #pragma unroll 8
    for (int n = 0; n < NN; n++) {
        float hrv = hr_s[n], hiv = hi_s[n], crv = cr[n], civ = ci[n];
        accr += hrv * crv - hiv * civ;
        acci += hrv * civ + hiv * crv;
    }
    size_t o = (size_t)row * DD + g * GDIM + t;
    yr[o] = accr;
    yi[o] = acci;
}

// ---------------------------------------------------------------------------
// K8: complex output GEMM + ssm_scale + residual, writes final (B,S,D,2).
__global__ __launch_bounds__(256) void k_out_gemm(
    const float* __restrict__ yr, const float* __restrict__ yi,
    const float* __restrict__ Wr, const float* __restrict__ Wi,
    const float* __restrict__ ssm,
    const float* __restrict__ xr0, const float* __restrict__ xi0,
    const float* __restrict__ res_scale, float* __restrict__ out)
{
    __shared__ float Ars[16][64];
    __shared__ float Ais[16][64];
    __shared__ float Wrs[16][64];
    __shared__ float Wis[16][64];
    int bm = blockIdx.y * 64, bn = blockIdx.x * 64;
    int tid = threadIdx.x;
    int tx = tid & 15, ty = tid >> 4;
    int lr = tid >> 2;
    int lk = (tid & 3) * 4;
    float accr[4][4] = {};
    float acci[4][4] = {};
    for (int k0 = 0; k0 < DD; k0 += 16) {
        float4 a = *(const float4*)&yr[(size_t)(bm + lr) * DD + k0 + lk];
        float4 b = *(const float4*)&yi[(size_t)(bm + lr) * DD + k0 + lk];
        float4 wr = *(const float4*)&Wr[(size_t)(bn + lr) * DD + k0 + lk];
        float4 wi = *(const float4*)&Wi[(size_t)(bn + lr) * DD + k0 + lk];
        __syncthreads();
        Ars[lk+0][lr] = a.x;  Ars[lk+1][lr] = a.y;  Ars[lk+2][lr] = a.z;  Ars[lk+3][lr] = a.w;
        Ais[lk+0][lr] = b.x;  Ais[lk+1][lr] = b.y;  Ais[lk+2][lr] = b.z;  Ais[lk+3][lr] = b.w;
        Wrs[lk+0][lr] = wr.x; Wrs[lk+1][lr] = wr.y; Wrs[lk+2][lr] = wr.z; Wrs[lk+3][lr] = wr.w;
        Wis[lk+0][lr] = wi.x; Wis[lk+1][lr] = wi.y; Wis[lk+2][lr] = wi.z; Wis[lk+3][lr] = wi.w;
        __syncthreads();
        #pragma unroll
        for (int k = 0; k < 16; k++) {
            float avr[4], avi[4], wvr[4], wvi[4];
            #pragma unroll
            for (int i = 0; i < 4; i++) {
                avr[i] = Ars[k][ty + 16*i]; avi[i] = Ais[k][ty + 16*i];
                wvr[i] = Wrs[k][tx + 16*i]; wvi[i] = Wis[k][tx + 16*i];
            }
            #pragma unroll
            for (int i = 0; i < 4; i++)
                #pragma unroll
                for (int j = 0; j < 4; j++) {
                    accr[i][j] += avr[i] * wvr[j] - avi[i] * wvi[j];
                    acci[i][j] += avr[i] * wvi[j] + avi[i] * wvr[j];
                }
        }
    }
    float rs = res_scale[0];
    #pragma unroll
    for (int i = 0; i < 4; i++) {
        int m = bm + ty + 16*i;
        #pragma unroll
        for (int j = 0; j < 4; j++) {
            int e = bn + tx + 16*j;
            float sc = ssm[e];
            size_t p = (size_t)m * DD + e;
            out[p*2]     = xr0[p] + rs * accr[i][j] * sc;
            out[p*2 + 1] = xi0[p] + rs * acci[i][j] * sc;
        }
    }
}

// ---------------------------------------------------------------------------
extern "C" void kernel_launch(void* const* d_in, const int* in_sizes, int n_in,
                              void* d_out, int out_size, void* d_ws, size_t ws_size,
                              hipStream_t stream) {
    const float* x_r      = (const float*)d_in[0];
    const float* x_i      = (const float*)d_in[1];
    const float* norm_w   = (const float*)d_in[2];
    const float* sg_theta = (const float*)d_in[3];
    const float* sg_Wg    = (const float*)d_in[4];
    const float* sg_bg    = (const float*)d_in[5];
    const float* conv_w   = (const float*)d_in[6];
    const float* conv_b   = (const float*)d_in[7];
    const float* log_A    = (const float*)d_in[8];
    const float* A_phase  = (const float*)d_in[9];
    const float* B_Wr     = (const float*)d_in[10];
    const float* B_Wi     = (const float*)d_in[11];
    const float* C_Wr     = (const float*)d_in[12];
    const float* C_Wi     = (const float*)d_in[13];
    const float* dt_W     = (const float*)d_in[14];
    const float* dt_b     = (const float*)d_in[15];
    const float* out_Wr   = (const float*)d_in[16];
    const float* out_Wi   = (const float*)d_in[17];
    const float* act_thr  = (const float*)d_in[18];
    const float* ssm_s    = (const float*)d_in[19];
    const float* res_s    = (const float*)d_in[20];
    float* out = (float*)d_out;
    float* ws  = (float*)d_ws;

    float* b_xr = ws;                 // normed xr -> rotated xr -> yr
    float* b_xi = ws + BSD;           // normed xi -> rotated xi -> yi
    float* b_a  = ws + 2*BSD;         // mag -> conv xr
    float* b_b  = ws + 3*BSD;         // gate -> conv xi
    float* p_ar = ws + 4*BSD;
    float* p_ai = p_ar + BSGN;
    float* p_br = p_ar + 2*BSGN;
    float* p_bi = p_ar + 3*BSGN;
    float* p_Hr = p_ar + 4*BSGN;
    float* p_Hi = p_ar + 5*BSGN;

    k_norm<<<BS, 256, 0, stream>>>(x_r, x_i, norm_w, b_xr, b_xi, b_a);
    k_gate_gemm<<<dim3(16, 256), 256, 0, stream>>>(b_a, sg_Wg, sg_bg, b_b);
    k_rotate<<<4096, 256, 0, stream>>>(b_xr, b_xi, b_b, sg_theta);
    k_conv<<<4096, 256, 0, stream>>>(b_xr, b_xi, conv_w, conv_b, act_thr, b_a, b_b);
    k_dtabx<<<BS, 512, 0, stream>>>(b_a, b_b, dt_W, dt_b, log_A, A_phase,
                                    B_Wr, B_Wi, p_ar, p_ai, p_br, p_bi);
    k_scan<<<32, 64, 0, stream>>>(p_ar, p_ai, p_br, p_bi, p_Hr, p_Hi);
    k_cproj<<<BS * GG, 128, 0, stream>>>(p_Hr, p_Hi, C_Wr, C_Wi, b_xr, b_xi);
    k_out_gemm<<<dim3(16, 256), 256, 0, stream>>>(b_xr, b_xi, out_Wr, out_Wi,
                                                  ssm_s, x_r, x_i, res_s, out);
}

// Round 2
// 2663.509 us; speedup vs baseline: 2.7240x; 2.7240x over previous
//
#include <hip/hip_runtime.h>
#include <hip/hip_bf16.h>
#include <math.h>

// Problem constants
#define BB 4
#define SS 4096
#define DD 1024
#define GG 8
#define NN 64
#define GDIM 128
#define BS (BB*SS)                    // 16384 rows
static const size_t BSD  = (size_t)BS * DD;      // 16,777,216
static const size_t BSGN = (size_t)BS * GG * NN; // 8,388,608

typedef __attribute__((ext_vector_type(8))) short bf16x8;
typedef __attribute__((ext_vector_type(4))) float f32x4;

__device__ inline ushort f2b(float x) {
    __hip_bfloat16 h = __float2bfloat16(x);
    return *reinterpret_cast<ushort*>(&h);
}

#define GL16(gp, lp) __builtin_amdgcn_global_load_lds( \
    (const __attribute__((address_space(1))) void*)(gp), \
    (__attribute__((address_space(3))) void*)(lp), 16, 0, 0)

// ---------------------------------------------------------------------------
// K0: weight prep. WgT_bf = bf16(Wg) [1024x1024]; WoT_bf [2048x2048]:
//   rows 0..1023 (o_r):  [Wr | -Wi];  rows 1024..2047 (o_i): [Wi | Wr]
__global__ __launch_bounds__(256) void k_prep_w(
    const float* __restrict__ Wg, const float* __restrict__ Wr,
    const float* __restrict__ Wi, ushort* __restrict__ WgT, ushort* __restrict__ WoT)
{
    const int total = 1048576 + 4194304;
    for (int idx = blockIdx.x * 256 + threadIdx.x; idx < total; idx += gridDim.x * 256) {
        if (idx < 1048576) {
            WgT[idx] = f2b(Wg[idx]);
        } else {
            int j = idx - 1048576;
            int row = j >> 11, k = j & 2047;
            float v;
            if (row < 1024) v = (k < 1024) ? Wr[row*1024 + k] : -Wi[row*1024 + (k-1024)];
            else { int e = row - 1024; v = (k < 1024) ? Wi[e*1024 + k] : Wr[e*1024 + (k-1024)]; }
            WoT[j] = f2b(v);
        }
    }
}

// ---------------------------------------------------------------------------
// K1: complex RMSNorm + magnitude (mag in bf16 for the MFMA gate GEMM).
__global__ __launch_bounds__(256) void k_norm(
    const float* __restrict__ xr_in, const float* __restrict__ xi_in,
    const float* __restrict__ norm_w,
    float* __restrict__ xr_o, float* __restrict__ xi_o, ushort* __restrict__ mag_o)
{
    int row = blockIdx.x;
    int tid = threadIdx.x;
    size_t base = (size_t)row * DD;
    float4 vr = ((const float4*)(xr_in + base))[tid];
    float4 vi = ((const float4*)(xi_in + base))[tid];
    float ss = vr.x*vr.x + vr.y*vr.y + vr.z*vr.z + vr.w*vr.w
             + vi.x*vi.x + vi.y*vi.y + vi.z*vi.z + vi.w*vi.w;
    #pragma unroll
    for (int off = 32; off >= 1; off >>= 1) ss += __shfl_down(ss, off);
    __shared__ float ws4[4];
    if ((tid & 63) == 0) ws4[tid >> 6] = ss;
    __syncthreads();
    float tot = ws4[0] + ws4[1] + ws4[2] + ws4[3];
    float inv = rsqrtf(tot * (1.0f / DD) + 1e-6f);
    float4 w = ((const float4*)norm_w)[tid];
    vr.x *= inv * w.x; vr.y *= inv * w.y; vr.z *= inv * w.z; vr.w *= inv * w.w;
    vi.x *= inv * w.x; vi.y *= inv * w.y; vi.z *= inv * w.z; vi.w *= inv * w.w;
    ushort4 mb;
    mb.x = f2b(sqrtf(vr.x*vr.x + vi.x*vi.x + 1e-8f));
    mb.y = f2b(sqrtf(vr.y*vr.y + vi.y*vi.y + 1e-8f));
    mb.z = f2b(sqrtf(vr.z*vr.z + vi.z*vi.z + 1e-8f));
    mb.w = f2b(sqrtf(vr.w*vr.w + vi.w*vi.w + 1e-8f));
    ((float4*)(xr_o + base))[tid] = vr;
    ((float4*)(xi_o + base))[tid] = vi;
    ((ushort4*)(mag_o + base))[tid] = mb;
}

// ---------------------------------------------------------------------------
// MFMA GEMM core (m97 structure): 128x128 tile, 4 waves, BK=32,
// A [M][K] bf16 row-major, B^T [N][K] bf16 row-major, global_load_lds staging.
// K2: gate = sigmoid(mag @ WgT + bg).  M=16384, N=1024, K=1024.
__global__ __launch_bounds__(256) void k_gate_mfma(
    const ushort* __restrict__ A, const ushort* __restrict__ B,
    const float* __restrict__ bg, float* __restrict__ gate)
{
    const int KD = 1024;
    __shared__ ushort lA[128*32];
    __shared__ ushort lB[128*32];
    int bm = blockIdx.y * 128, bn = blockIdx.x * 128;
    int tid = threadIdx.x;
    int wave = tid >> 6, lane = tid & 63;
    int r = lane & 15, h = lane >> 4;
    int wm = (wave & 1) * 64, wn = (wave >> 1) * 64;

    int row0 = wave*32 + (lane >> 2);
    int col0 = (lane & 3) * 8;
    const ushort* gA = A + (size_t)(bm + row0) * KD + col0;
    const ushort* gB = B + (size_t)(bn + row0) * KD + col0;
    ushort* lA0 = lA + wave*1024;
    ushort* lB0 = lB + wave*1024;

    f32x4 acc[4][4] = {};
    for (int k0 = 0; k0 < KD; k0 += 32) {
        __syncthreads();
        GL16(gA + k0,            lA0);
        GL16(gA + k0 + 16*KD,    lA0 + 512);
        GL16(gB + k0,            lB0);
        GL16(gB + k0 + 16*KD,    lB0 + 512);
        __syncthreads();
        bf16x8 af[4], bf_[4];
        #pragma unroll
        for (int i = 0; i < 4; i++) af[i]  = *(const bf16x8*)&lA[(wm + i*16 + r)*32 + h*8];
        #pragma unroll
        for (int j = 0; j < 4; j++) bf_[j] = *(const bf16x8*)&lB[(wn + j*16 + r)*32 + h*8];
        #pragma unroll
        for (int i = 0; i < 4; i++)
            #pragma unroll
            for (int j = 0; j < 4; j++)
                acc[i][j] = __builtin_amdgcn_mfma_f32_16x16x32_bf16(af[i], bf_[j], acc[i][j], 0, 0, 0);
    }
    #pragma unroll
    for (int i = 0; i < 4; i++) {
        int mb = bm + wm + i*16 + h*4;
        #pragma unroll
        for (int j = 0; j < 4; j++) {
            int n = bn + wn + j*16 + r;
            float bias = bg[n];
            #pragma unroll
            for (int t2 = 0; t2 < 4; t2++) {
                float v = acc[i][j][t2] + bias;
                gate[(size_t)(mb + t2)*DD + n] = 1.0f / (1.0f + expf(-v));
            }
        }
    }
}

// K8: out complex GEMM fused: C = [yr|yi] @ WoT^T, N=2048 (real|imag), K=2048.
__global__ __launch_bounds__(256) void k_out_mfma(
    const ushort* __restrict__ A, const ushort* __restrict__ B,
    const float* __restrict__ ssm,
    const float* __restrict__ xr0, const float* __restrict__ xi0,
    const float* __restrict__ res_scale, float* __restrict__ out)
{
    const int KD = 2048;
    __shared__ ushort lA[128*32];
    __shared__ ushort lB[128*32];
    int bm = blockIdx.y * 128, bn = blockIdx.x * 128;
    int tid = threadIdx.x;
    int wave = tid >> 6, lane = tid & 63;
    int r = lane & 15, h = lane >> 4;
    int wm = (wave & 1) * 64, wn = (wave >> 1) * 64;

    int row0 = wave*32 + (lane >> 2);
    int col0 = (lane & 3) * 8;
    const ushort* gA = A + (size_t)(bm + row0) * KD + col0;
    const ushort* gB = B + (size_t)(bn + row0) * KD + col0;
    ushort* lA0 = lA + wave*1024;
    ushort* lB0 = lB + wave*1024;

    f32x4 acc[4][4] = {};
    for (int k0 = 0; k0 < KD; k0 += 32) {
        __syncthreads();
        GL16(gA + k0,            lA0);
        GL16(gA + k0 + 16*KD,    lA0 + 512);
        GL16(gB + k0,            lB0);
        GL16(gB + k0 + 16*KD,    lB0 + 512);
        __syncthreads();
        bf16x8 af[4], bf_[4];
        #pragma unroll
        for (int i = 0; i < 4; i++) af[i]  = *(const bf16x8*)&lA[(wm + i*16 + r)*32 + h*8];
        #pragma unroll
        for (int j = 0; j < 4; j++) bf_[j] = *(const bf16x8*)&lB[(wn + j*16 + r)*32 + h*8];
        #pragma unroll
        for (int i = 0; i < 4; i++)
            #pragma unroll
            for (int j = 0; j < 4; j++)
                acc[i][j] = __builtin_amdgcn_mfma_f32_16x16x32_bf16(af[i], bf_[j], acc[i][j], 0, 0, 0);
    }
    float rs = res_scale[0];
    bool isReal = (bn < 1024);           // tile is entirely in one half (1024%128==0)
    #pragma unroll
    for (int i = 0; i < 4; i++) {
        int mb = bm + wm + i*16 + h*4;
        #pragma unroll
        for (int j = 0; j < 4; j++) {
            int n = bn + wn + j*16 + r;
            int e = n & 1023;
            float sc = ssm[e] * rs;
            #pragma unroll
            for (int t2 = 0; t2 < 4; t2++) {
                size_t p = (size_t)(mb + t2)*DD + e;
                if (isReal) out[2*p]     = xr0[p] + acc[i][j][t2]*sc;
                else        out[2*p + 1] = xi0[p] + acc[i][j][t2]*sc;
            }
        }
    }
}

// ---------------------------------------------------------------------------
// K3: rotate by theta and apply gate, in place.
__global__ __launch_bounds__(256) void k_rotate(
    float* __restrict__ xr, float* __restrict__ xi,
    const float* __restrict__ gate, const float* __restrict__ theta)
{
    size_t total = BSD;
    for (size_t idx = (size_t)blockIdx.x * blockDim.x + threadIdx.x;
         idx < total; idx += (size_t)gridDim.x * blockDim.x) {
        int d = (int)(idx & (DD - 1));
        float th = theta[d >> 3];
        float st, ct;
        sincosf(th, &st, &ct);
        float r = xr[idx], im = xi[idx], g = gate[idx];
        xr[idx] = g * (r * ct - im * st);
        xi[idx] = g * (r * st + im * ct);
    }
}

// ---------------------------------------------------------------------------
// K4: depthwise causal conv (K=4) + activation.
__global__ __launch_bounds__(256) void k_conv(
    const float* __restrict__ xr, const float* __restrict__ xi,
    const float* __restrict__ cw, const float* __restrict__ cb,
    const float* __restrict__ act_thr,
    float* __restrict__ cxr, float* __restrict__ cxi)
{
    float ea = expf(act_thr[0]);
    size_t total = BSD;
    for (size_t idx = (size_t)blockIdx.x * blockDim.x + threadIdx.x;
         idx < total; idx += (size_t)gridDim.x * blockDim.x) {
        int d = (int)(idx & (DD - 1));
        size_t bs = idx >> 10;
        int s = (int)(bs & (SS - 1));
        float w0r[4], w0i[4], w1r[4], w1i[4];
        *(float4*)w0r = *(const float4*)&cw[(size_t)(2*d) * 8 + 0];
        *(float4*)w0i = *(const float4*)&cw[(size_t)(2*d) * 8 + 4];
        *(float4*)w1r = *(const float4*)&cw[(size_t)(2*d) * 8 + 8];
        *(float4*)w1i = *(const float4*)&cw[(size_t)(2*d) * 8 + 12];
        float cr = cb[2*d], ci = cb[2*d + 1];
        #pragma unroll
        for (int k = 0; k < 4; k++) {
            int sp = s - 3 + k;
            if (sp < 0) continue;
            size_t p = idx + ((size_t)(sp - s)) * DD;
            float vr = xr[p], vi = xi[p];
            cr += vr * w0r[k] + vi * w0i[k];
            ci += vr * w1r[k] + vi * w1i[k];
        }
        float act = 1.0f - expf(-(cr*cr + ci*ci) * ea);
        cxr[idx] = cr * act;
        cxi[idx] = ci * act;
    }
}

// ---------------------------------------------------------------------------
// K5: per (b,s): dt, a, bx.
__global__ __launch_bounds__(512) void k_dtabx(
    const float* __restrict__ cxr, const float* __restrict__ cxi,
    const float* __restrict__ dtW, const float* __restrict__ dtb,
    const float* __restrict__ logA, const float* __restrict__ Aph,
    const float* __restrict__ BWr, const float* __restrict__ BWi,
    float* __restrict__ o_ar, float* __restrict__ o_ai,
    float* __restrict__ o_br, float* __restrict__ o_bi)
{
    int row = blockIdx.x;
    int tid = threadIdx.x;
    int g = tid >> 6, n = tid & 63;
    __shared__ float sr[DD];
    __shared__ float si[DD];
    size_t base = (size_t)row * DD;
    ((float2*)sr)[tid] = ((const float2*)(cxr + base))[tid];
    ((float2*)si)[tid] = ((const float2*)(cxi + base))[tid];
    __syncthreads();
    const float* xgr = sr + g * GDIM;
    const float* xgi = si + g * GDIM;
    float p0 = xgr[n]*dtW[n]       + xgr[n+64]*dtW[n+64]
             + xgi[n]*dtW[128+n]   + xgi[n+64]*dtW[192+n];
    float p1 = xgr[n]*dtW[256+n]   + xgr[n+64]*dtW[256+n+64]
             + xgi[n]*dtW[256+128+n] + xgi[n+64]*dtW[256+192+n];
    #pragma unroll
    for (int off = 32; off >= 1; off >>= 1) {
        p0 += __shfl_down(p0, off);
        p1 += __shfl_down(p1, off);
    }
    p0 = __shfl(p0, 0);
    p1 = __shfl(p1, 0);
    float dtm = fminf(fmaxf(expf(p0 + dtb[0]), 1e-4f), 2.0f);
    float dtp = fminf(fmaxf(expf(p1 + dtb[1]), 1e-4f), 2.0f);
    float la = logA[g * NN + n];
    float spl = log1pf(expf(la));
    float am = expf(-dtm * spl);
    float ang = dtp * Aph[g * NN + n];
    float sa, ca;
    sincosf(ang, &sa, &ca);
    const float* wr = BWr + (size_t)n * GDIM;
    const float* wi = BWi + (size_t)n * GDIM;
    float pr = 0.f, qi = 0.f, ur = 0.f, vi = 0.f;
    #pragma unroll 8
    for (int d = 0; d < GDIM; d++) {
        float xr = xgr[d], xi = xgi[d], wrd = wr[d], wid = wi[d];
        pr += xr * wrd; qi += xi * wid;
        ur += xr * wid; vi += xi * wrd;
    }
    size_t o = (size_t)row * (GG * NN) + tid;
    o_ar[o] = am * ca;
    o_ai[o] = am * sa;
    o_br[o] = (pr - qi) * dtm;
    o_bi[o] = (ur + vi) * dtm;
}

// ---------------------------------------------------------------------------
// K6: chunked parallel scan.  Chunk = 256 steps (renorm fires only at chunk
// ends, so each chunk is a linear map h_out = A*h_in + B).
// scan1: per (b, chunk, gn-slice) compute composed (A,B).
__global__ __launch_bounds__(128) void k_scan1(
    const float* __restrict__ ar, const float* __restrict__ ai,
    const float* __restrict__ br, const float* __restrict__ bi,
    float* __restrict__ Sar, float* __restrict__ Sai,
    float* __restrict__ Sbr, float* __restrict__ Sbi)
{
    int blk = blockIdx.x;            // 256 = 4b * 16c * 4slice
    int sl = blk & 3, c = (blk >> 2) & 15, b = blk >> 6;
    int t = sl * 128 + threadIdx.x;  // 0..511
    size_t idx = ((size_t)b * SS + (size_t)c * 256) * 512 + t;
    float Ar = 1.f, Ai = 0.f, Br = 0.f, Bi = 0.f;
    for (int s0 = 0; s0 < 256; s0 += 8) {
        float va[8], vb[8], wr[8], wi[8];
        #pragma unroll
        for (int u = 0; u < 8; u++) {
            size_t p = idx + (size_t)u * 512;
            va[u] = ar[p]; vb[u] = ai[p]; wr[u] = br[p]; wi[u] = bi[p];
        }
        #pragma unroll
        for (int u = 0; u < 8; u++) {
            float nBr = va[u]*Br - vb[u]*Bi + wr[u];
            float nBi = va[u]*Bi + vb[u]*Br + wi[u];
            float nAr = va[u]*Ar - vb[u]*Ai;
            float nAi = va[u]*Ai + vb[u]*Ar;
            Br = nBr; Bi = nBi; Ar = nAr; Ai = nAi;
        }
        idx += (size_t)8 * 512;
    }
    size_t o = ((size_t)b * 16 + c) * 512 + t;
    Sar[o] = Ar; Sai[o] = Ai; Sbr[o] = Br; Sbi[o] = Bi;
}

// scan2: sequential over 16 chunks per chain, with the end-of-chunk clamp.
__global__ __launch_bounds__(128) void k_scan2(
    const float* __restrict__ Sar, const float* __restrict__ Sai,
    const float* __restrict__ Sbr, const float* __restrict__ Sbi,
    float* __restrict__ hinr, float* __restrict__ hini)
{
    int blk = blockIdx.x;            // 16 = 4b * 4slice
    int sl = blk & 3, b = blk >> 2;
    int t = sl * 128 + threadIdx.x;
    float hr = 0.f, hi = 0.f;
    for (int c = 0; c < 16; c++) {
        size_t o = ((size_t)b * 16 + c) * 512 + t;
        hinr[o] = hr; hini[o] = hi;
        float nr = Sar[o]*hr - Sai[o]*hi + Sbr[o];
        float ni = Sar[o]*hi + Sai[o]*hr + Sbi[o];
        float hn = sqrtf(nr*nr + ni*ni + 1e-8f);
        float sc = fminf(hn, 100.0f) / hn;
        hr = nr * sc; hi = ni * sc;
    }
}

// scan3: recompute chunk states from h_in; write H in place over ar/ai.
__global__ __launch_bounds__(128) void k_scan3(
    float* ar, float* ai, const float* br, const float* bi,
    const float* __restrict__ hinr, const float* __restrict__ hini)
{
    int blk = blockIdx.x;
    int sl = blk & 3, c = (blk >> 2) & 15, b = blk >> 6;
    int t = sl * 128 + threadIdx.x;
    size_t idx = ((size_t)b * SS + (size_t)c * 256) * 512 + t;
    size_t o = ((size_t)b * 16 + c) * 512 + t;
    float hr = hinr[o], hi = hini[o];
    for (int s0 = 0; s0 < 256; s0 += 8) {
        float va[8], vb[8], wr[8], wi[8];
        #pragma unroll
        for (int u = 0; u < 8; u++) {
            size_t p = idx + (size_t)u * 512;
            va[u] = ar[p]; vb[u] = ai[p]; wr[u] = br[p]; wi[u] = bi[p];
        }
        #pragma unroll
        for (int u = 0; u < 8; u++) {
            float nr = va[u]*hr - vb[u]*hi + wr[u];
            float ni = va[u]*hi + vb[u]*hr + wi[u];
            if (s0 + u == 255) {
                float hn = sqrtf(nr*nr + ni*ni + 1e-8f);
                float sc = fminf(hn, 100.0f) / hn;
                nr *= sc; ni *= sc;
            }
            size_t p = idx + (size_t)u * 512;
            ar[p] = nr; ai[p] = ni;
            hr = nr; hi = ni;
        }
        idx += (size_t)8 * 512;
    }
}

// ---------------------------------------------------------------------------
// K7: y = H @ C (complex); writes bf16 A-matrix [yr|yi] for the out GEMM.
__global__ __launch_bounds__(128) void k_cproj(
    const float* __restrict__ Hr, const float* __restrict__ Hi,
    const float* __restrict__ CWr, const float* __restrict__ CWi,
    ushort* __restrict__ ybf)
{
    int bid = blockIdx.x;       // row*8 + g
    int row = bid >> 3, g = bid & 7;
    int t = threadIdx.x;        // 0..127
    __shared__ float hr_s[NN];
    __shared__ float hi_s[NN];
    size_t hbase = (size_t)row * (GG * NN) + g * NN;
    if (t < 64) hr_s[t] = Hr[hbase + t];
    else        hi_s[t - 64] = Hi[hbase + t - 64];
    __syncthreads();
    const float* cr = CWr + (size_t)t * NN;
    const float* ci = CWi + (size_t)t * NN;
    float accr = 0.f, acci = 0.f;
    #pragma unroll 8
    for (int n = 0; n < NN; n++) {
        float hrv = hr_s[n], hiv = hi_s[n], crv = cr[n], civ = ci[n];
        accr += hrv * crv - hiv * civ;
        acci += hrv * civ + hiv * crv;
    }
    size_t ob = (size_t)row * 2048 + g * GDIM + t;
    ybf[ob]        = f2b(accr);
    ybf[ob + 1024] = f2b(acci);
}

// ---------------------------------------------------------------------------
extern "C" void kernel_launch(void* const* d_in, const int* in_sizes, int n_in,
                              void* d_out, int out_size, void* d_ws, size_t ws_size,
                              hipStream_t stream) {
    const float* x_r      = (const float*)d_in[0];
    const float* x_i      = (const float*)d_in[1];
    const float* norm_w   = (const float*)d_in[2];
    const float* sg_theta = (const float*)d_in[3];
    const float* sg_Wg    = (const float*)d_in[4];
    const float* sg_bg    = (const float*)d_in[5];
    const float* conv_w   = (const float*)d_in[6];
    const float* conv_b   = (const float*)d_in[7];
    const float* log_A    = (const float*)d_in[8];
    const float* A_phase  = (const float*)d_in[9];
    const float* B_Wr     = (const float*)d_in[10];
    const float* B_Wi     = (const float*)d_in[11];
    const float* C_Wr     = (const float*)d_in[12];
    const float* C_Wi     = (const float*)d_in[13];
    const float* dt_W     = (const float*)d_in[14];
    const float* dt_b     = (const float*)d_in[15];
    const float* out_Wr   = (const float*)d_in[16];
    const float* out_Wi   = (const float*)d_in[17];
    const float* act_thr  = (const float*)d_in[18];
    const float* ssm_s    = (const float*)d_in[19];
    const float* res_s    = (const float*)d_in[20];
    float* out = (float*)d_out;
    float* ws  = (float*)d_ws;

    // f32 big buffers
    float* A = ws;               // normed/rotated xr
    float* Bv = ws + BSD;        // normed/rotated xi
    float* C = ws + 2*BSD;       // gate -> cxr
    float* D = ws + 3*BSD;       // cxi;  later reused as ybf (bf16, 64MiB)
    // scan state buffers
    float* p_ar = ws + 4*BSD;    // also mag_bf region before dtabx
    float* p_ai = p_ar + BSGN;
    float* p_br = p_ar + 2*BSGN;
    float* p_bi = p_ar + 3*BSGN;
    // tail: small buffers
    float* tail = ws + 4*BSD + 4*BSGN;
    ushort* WgT = (ushort*)tail;                         // 1Mi ushorts = 524288 floats
    ushort* WoT = (ushort*)(tail + 524288);              // 4Mi ushorts = 2097152 floats
    float* Sar  = tail + 524288 + 2097152;               // 6 x 32768 floats
    float* Sai  = Sar + 32768;
    float* Sbr  = Sar + 2*32768;
    float* Sbi  = Sar + 3*32768;
    float* hinr = Sar + 4*32768;
    float* hini = Sar + 5*32768;
    ushort* mag_bf = (ushort*)p_ar;                      // 32MiB, dead before dtabx
    ushort* ybf    = (ushort*)D;                         // 64MiB, after dtabx

    k_prep_w<<<256, 256, 0, stream>>>(sg_Wg, out_Wr, out_Wi, WgT, WoT);
    k_norm<<<BS, 256, 0, stream>>>(x_r, x_i, norm_w, A, Bv, mag_bf);
    k_gate_mfma<<<dim3(8, 128), 256, 0, stream>>>(mag_bf, WgT, sg_bg, C);
    k_rotate<<<4096, 256, 0, stream>>>(A, Bv, C, sg_theta);
    k_conv<<<4096, 256, 0, stream>>>(A, Bv, conv_w, conv_b, act_thr, C, D);
    k_dtabx<<<BS, 512, 0, stream>>>(C, D, dt_W, dt_b, log_A, A_phase,
                                    B_Wr, B_Wi, p_ar, p_ai, p_br, p_bi);
    k_scan1<<<256, 128, 0, stream>>>(p_ar, p_ai, p_br, p_bi, Sar, Sai, Sbr, Sbi);
    k_scan2<<<16, 128, 0, stream>>>(Sar, Sai, Sbr, Sbi, hinr, hini);
    k_scan3<<<256, 128, 0, stream>>>(p_ar, p_ai, p_br, p_bi, hinr, hini);
    k_cproj<<<BS * GG, 128, 0, stream>>>(p_ar, p_ai, C_Wr, C_Wi, ybf);
    k_out_mfma<<<dim3(16, 128), 256, 0, stream>>>(ybf, WoT, ssm_s, x_r, x_i, res_s, out);
}

// Round 3
// 654.008 us; speedup vs baseline: 11.0936x; 4.0726x over previous
//
#include <hip/hip_runtime.h>
#include <hip/hip_bf16.h>
#include <math.h>

// Problem constants
#define BB 4
#define SS 4096
#define DD 1024
#define GG 8
#define NN 64
#define GDIM 128
#define BS (BB*SS)                    // 16384 rows
static const size_t BSD  = (size_t)BS * DD;      // 16,777,216
static const size_t BSGN = (size_t)BS * GG * NN; // 8,388,608

typedef __attribute__((ext_vector_type(8))) short bf16x8;
typedef __attribute__((ext_vector_type(4))) float f32x4;

__device__ inline ushort f2b(float x) {
    __hip_bfloat16 h = __float2bfloat16(x);
    return *reinterpret_cast<ushort*>(&h);
}

#define GL16(gp, lp) __builtin_amdgcn_global_load_lds( \
    (const __attribute__((address_space(1))) void*)(gp), \
    (__attribute__((address_space(3))) void*)(lp), 16, 0, 0)

// ---------------------------------------------------------------------------
// Shared MFMA GEMM core (m97 structure): 128x128 tile, 4 waves, BK=32.
// A [M][LDA] bf16 row-major (gA pre-offset to tile+lane), B^T [N][LDB].
template<int KD, int LDA, int LDB>
__device__ __forceinline__ void mfma_core(
    const ushort* __restrict__ gA, const ushort* __restrict__ gB,
    ushort* lA, ushort* lB, int wave, int lane, f32x4 (&acc)[4][4])
{
    int r = lane & 15, h = lane >> 4;
    int wm = (wave & 1) * 64, wn = (wave >> 1) * 64;
    ushort* lA0 = lA + wave * 1024;
    ushort* lB0 = lB + wave * 1024;
    for (int k0 = 0; k0 < KD; k0 += 32) {
        __syncthreads();
        GL16(gA + k0,            lA0);
        GL16(gA + k0 + 16*LDA,   lA0 + 512);
        GL16(gB + k0,            lB0);
        GL16(gB + k0 + 16*LDB,   lB0 + 512);
        __syncthreads();
        bf16x8 af[4], bfv[4];
        #pragma unroll
        for (int i = 0; i < 4; i++) af[i]  = *(const bf16x8*)&lA[(wm + i*16 + r)*32 + h*8];
        #pragma unroll
        for (int j = 0; j < 4; j++) bfv[j] = *(const bf16x8*)&lB[(wn + j*16 + r)*32 + h*8];
        #pragma unroll
        for (int i = 0; i < 4; i++)
            #pragma unroll
            for (int j = 0; j < 4; j++)
                acc[i][j] = __builtin_amdgcn_mfma_f32_16x16x32_bf16(af[i], bfv[j], acc[i][j], 0, 0, 0);
    }
}

// ---------------------------------------------------------------------------
// K0: prep.  WgT = bf16(Wg);  BxT [128][256]: rows n<64 [BWr|-BWi], n>=64 [BWi|BWr];
// A3 [128][256]: rows m<64 [Cr^T|-Ci^T], m>=64 [Ci^T|Cr^T];
// Wo_pack [1024 e][2048]: [e][g*256+kk] = kk<128 ? Wr[e][g*128+kk] : Wi[e][g*128+kk-128];
// spl[512] = softplus(logA).
__global__ __launch_bounds__(256) void k_prep(
    const float* __restrict__ Wg, const float* __restrict__ BWr, const float* __restrict__ BWi,
    const float* __restrict__ CWr, const float* __restrict__ CWi,
    const float* __restrict__ Wor, const float* __restrict__ Woi,
    const float* __restrict__ logA,
    ushort* __restrict__ WgT, ushort* __restrict__ BxT, ushort* __restrict__ A3,
    ushort* __restrict__ WoP, float* __restrict__ spl)
{
    const int S1 = 1048576;           // WgT
    const int S2 = S1 + 32768;        // BxT
    const int S3 = S2 + 32768;        // A3
    const int S4 = S3 + 2097152;      // WoP
    const int S5 = S4 + 512;          // spl
    for (int idx = blockIdx.x * 256 + threadIdx.x; idx < S5; idx += gridDim.x * 256) {
        if (idx < S1) {
            WgT[idx] = f2b(Wg[idx]);
        } else if (idx < S2) {
            int j = idx - S1, n = j >> 8, kk = j & 255;
            float v;
            if (n < 64) v = (kk < 128) ? BWr[n*128 + kk] : -BWi[n*128 + (kk-128)];
            else { int n2 = n - 64; v = (kk < 128) ? BWi[n2*128 + kk] : BWr[n2*128 + (kk-128)]; }
            BxT[j] = f2b(v);
        } else if (idx < S3) {
            int j = idx - S2, m = j >> 8, kk = j & 255;
            float v;
            if (m < 64) v = (kk < 128) ? CWr[kk*64 + m] : -CWi[(kk-128)*64 + m];
            else { int n2 = m - 64; v = (kk < 128) ? CWi[kk*64 + n2] : CWr[(kk-128)*64 + n2]; }
            A3[j] = f2b(v);
        } else if (idx < S4) {
            int j = idx - S3, e = j >> 11, c = j & 2047;
            int g = c >> 8, kk = c & 255;
            float v = (kk < 128) ? Wor[(size_t)e*1024 + g*128 + kk]
                                 : Woi[(size_t)e*1024 + g*128 + (kk-128)];
            WoP[j] = f2b(v);
        } else {
            int j = idx - S4;
            spl[j] = log1pf(expf(logA[j]));
        }
    }
}

// ---------------------------------------------------------------------------
// K0b: P = C-combined-with-Wo.  Per g: [Pr;Pi](128x1024) = A3(128x256) @ WoP_g^T.
// Epilogue packs Bbig [2048][1024] bf16 for the out GEMM.
__global__ __launch_bounds__(256) void k_pgemm(
    const ushort* __restrict__ A3, const ushort* __restrict__ WoP,
    ushort* __restrict__ Bbig)
{
    __shared__ ushort lA[4096], lB[4096];
    int g = blockIdx.z;
    int bn = blockIdx.x * 128;
    int tid = threadIdx.x, wave = tid >> 6, lane = tid & 63;
    int row0 = wave*32 + (lane >> 2), col0 = (lane & 3) * 8;
    int r = lane & 15, h = lane >> 4;
    int wm = (wave & 1) * 64, wn = (wave >> 1) * 64;
    f32x4 acc[4][4] = {};
    mfma_core<256, 256, 2048>(A3 + (size_t)row0*256 + col0,
                              WoP + (size_t)(bn + row0)*2048 + g*256 + col0,
                              lA, lB, wave, lane, acc);
    #pragma unroll
    for (int i = 0; i < 4; i++) {
        int mb = wm + i*16 + h*4;
        #pragma unroll
        for (int j = 0; j < 4; j++) {
            int e = bn + wn + j*16 + r;
            #pragma unroll
            for (int t2 = 0; t2 < 4; t2++) {
                int m = mb + t2;
                float v = acc[i][j][t2];
                if (m < 64) {
                    int col = g*64 + m;
                    Bbig[(size_t)e*1024 + col] = f2b(v);
                    Bbig[(size_t)(1024 + e)*1024 + 512 + col] = f2b(v);
                } else {
                    int col = g*64 + (m - 64);
                    Bbig[(size_t)e*1024 + 512 + col] = f2b(-v);
                    Bbig[(size_t)(1024 + e)*1024 + col] = f2b(v);
                }
            }
        }
    }
}

// ---------------------------------------------------------------------------
// K1: complex RMSNorm + magnitude (bf16).
__global__ __launch_bounds__(256) void k_norm(
    const float* __restrict__ xr_in, const float* __restrict__ xi_in,
    const float* __restrict__ norm_w,
    float* __restrict__ xr_o, float* __restrict__ xi_o, ushort* __restrict__ mag_o)
{
    int row = blockIdx.x;
    int tid = threadIdx.x;
    size_t base = (size_t)row * DD;
    float4 vr = ((const float4*)(xr_in + base))[tid];
    float4 vi = ((const float4*)(xi_in + base))[tid];
    float ss = vr.x*vr.x + vr.y*vr.y + vr.z*vr.z + vr.w*vr.w
             + vi.x*vi.x + vi.y*vi.y + vi.z*vi.z + vi.w*vi.w;
    #pragma unroll
    for (int off = 32; off >= 1; off >>= 1) ss += __shfl_down(ss, off);
    __shared__ float ws4[4];
    if ((tid & 63) == 0) ws4[tid >> 6] = ss;
    __syncthreads();
    float tot = ws4[0] + ws4[1] + ws4[2] + ws4[3];
    float inv = rsqrtf(tot * (1.0f / DD) + 1e-6f);
    float4 w = ((const float4*)norm_w)[tid];
    vr.x *= inv * w.x; vr.y *= inv * w.y; vr.z *= inv * w.z; vr.w *= inv * w.w;
    vi.x *= inv * w.x; vi.y *= inv * w.y; vi.z *= inv * w.z; vi.w *= inv * w.w;
    ushort4 mb;
    mb.x = f2b(sqrtf(vr.x*vr.x + vi.x*vi.x + 1e-8f));
    mb.y = f2b(sqrtf(vr.y*vr.y + vi.y*vi.y + 1e-8f));
    mb.z = f2b(sqrtf(vr.z*vr.z + vi.z*vi.z + 1e-8f));
    mb.w = f2b(sqrtf(vr.w*vr.w + vi.w*vi.w + 1e-8f));
    ((float4*)(xr_o + base))[tid] = vr;
    ((float4*)(xi_o + base))[tid] = vi;
    ((ushort4*)(mag_o + base))[tid] = mb;
}

// ---------------------------------------------------------------------------
// K2: gate = sigmoid(mag @ Wg^T + bg).  M=16384, N=1024, K=1024.
__global__ __launch_bounds__(256) void k_gate_mfma(
    const ushort* __restrict__ A, const ushort* __restrict__ B,
    const float* __restrict__ bg, float* __restrict__ gate)
{
    __shared__ ushort lA[4096], lB[4096];
    int bm = blockIdx.y * 128, bn = blockIdx.x * 128;
    int tid = threadIdx.x, wave = tid >> 6, lane = tid & 63;
    int row0 = wave*32 + (lane >> 2), col0 = (lane & 3) * 8;
    int r = lane & 15, h = lane >> 4;
    int wm = (wave & 1) * 64, wn = (wave >> 1) * 64;
    f32x4 acc[4][4] = {};
    mfma_core<1024, 1024, 1024>(A + (size_t)(bm + row0)*1024 + col0,
                                B + (size_t)(bn + row0)*1024 + col0,
                                lA, lB, wave, lane, acc);
    #pragma unroll
    for (int i = 0; i < 4; i++) {
        int mb = bm + wm + i*16 + h*4;
        #pragma unroll
        for (int j = 0; j < 4; j++) {
            int n = bn + wn + j*16 + r;
            float bias = bg[n];
            #pragma unroll
            for (int t2 = 0; t2 < 4; t2++) {
                float v = acc[i][j][t2] + bias;
                gate[(size_t)(mb + t2)*DD + n] = 1.0f / (1.0f + expf(-v));
            }
        }
    }
}

// ---------------------------------------------------------------------------
// K3: rotate by theta and apply gate, in place.
__global__ __launch_bounds__(256) void k_rotate(
    float* __restrict__ xr, float* __restrict__ xi,
    const float* __restrict__ gate, const float* __restrict__ theta)
{
    size_t total = BSD;
    for (size_t idx = (size_t)blockIdx.x * blockDim.x + threadIdx.x;
         idx < total; idx += (size_t)gridDim.x * blockDim.x) {
        int d = (int)(idx & (DD - 1));
        float th = theta[d >> 3];
        float st, ct;
        sincosf(th, &st, &ct);
        float r = xr[idx], im = xi[idx], g = gate[idx];
        xr[idx] = g * (r * ct - im * st);
        xi[idx] = g * (r * st + im * ct);
    }
}

// ---------------------------------------------------------------------------
// K4: fused depthwise conv (K=4) + activation + bf16 xcat + dt reduction.
// One block per (b,s) row; thread t handles d = 4t..4t+3.
__global__ __launch_bounds__(256) void k_convdt(
    const float* __restrict__ xr, const float* __restrict__ xi,
    const float* __restrict__ cw, const float* __restrict__ cb,
    const float* __restrict__ act_thr,
    const float* __restrict__ dtW, const float* __restrict__ dtb,
    ushort* __restrict__ xcat, float* __restrict__ dtm_o, float* __restrict__ dtp_o)
{
    int row = blockIdx.x;
    int s = row & (SS - 1);
    int t = threadIdx.x;
    int d0 = t * 4;
    size_t base = (size_t)row * DD + d0;
    float4 x0r = {0,0,0,0}, x0i = {0,0,0,0};
    float4 x1r = {0,0,0,0}, x1i = {0,0,0,0};
    float4 x2r = {0,0,0,0}, x2i = {0,0,0,0};
    float4 x3r = *(const float4*)&xr[base];
    float4 x3i = *(const float4*)&xi[base];
    if (s >= 1) { x2r = *(const float4*)&xr[base - DD];   x2i = *(const float4*)&xi[base - DD]; }
    if (s >= 2) { x1r = *(const float4*)&xr[base - 2*DD]; x1i = *(const float4*)&xi[base - 2*DD]; }
    if (s >= 3) { x0r = *(const float4*)&xr[base - 3*DD]; x0i = *(const float4*)&xi[base - 3*DD]; }
    float ea = expf(act_thr[0]);
    const float* xr4[4] = { (const float*)&x0r, (const float*)&x1r, (const float*)&x2r, (const float*)&x3r };
    const float* xi4[4] = { (const float*)&x0i, (const float*)&x1i, (const float*)&x2i, (const float*)&x3i };
    float cr4[4], ci4[4];
    #pragma unroll
    for (int j = 0; j < 4; j++) {
        int d = d0 + j;
        const float* w = &cw[(size_t)(2*d) * 8];   // [w0r(4) w0i(4) w1r(4) w1i(4)]
        float cr = cb[2*d], ci = cb[2*d + 1];
        #pragma unroll
        for (int k = 0; k < 4; k++) {
            float vr = xr4[k][j], vi = xi4[k][j];
            cr += vr * w[k]     + vi * w[4 + k];
            ci += vr * w[8 + k] + vi * w[12 + k];
        }
        float act = 1.0f - expf(-(cr*cr + ci*ci) * ea);
        cr4[j] = cr * act;
        ci4[j] = ci * act;
    }
    int g = d0 >> 7, dd = d0 & 127;
    ushort4 ur, ui;
    ur.x = f2b(cr4[0]); ur.y = f2b(cr4[1]); ur.z = f2b(cr4[2]); ur.w = f2b(cr4[3]);
    ui.x = f2b(ci4[0]); ui.y = f2b(ci4[1]); ui.z = f2b(ci4[2]); ui.w = f2b(ci4[3]);
    *(ushort4*)&xcat[(size_t)row*2048 + g*256 + dd]       = ur;
    *(ushort4*)&xcat[(size_t)row*2048 + g*256 + 128 + dd] = ui;
    // dt reduction (f32, group = 32 consecutive threads)
    float p0 = 0.f, p1 = 0.f;
    #pragma unroll
    for (int j = 0; j < 4; j++) {
        p0 += cr4[j]*dtW[dd + j]       + ci4[j]*dtW[128 + dd + j];
        p1 += cr4[j]*dtW[256 + dd + j] + ci4[j]*dtW[384 + dd + j];
    }
    #pragma unroll
    for (int off = 16; off >= 1; off >>= 1) {
        p0 += __shfl_down(p0, off, 32);
        p1 += __shfl_down(p1, off, 32);
    }
    if ((t & 31) == 0) {
        dtm_o[(size_t)row*8 + g] = fminf(fmaxf(expf(p0 + dtb[0]), 1e-4f), 2.0f);
        dtp_o[(size_t)row*8 + g] = fminf(fmaxf(expf(p1 + dtb[1]), 1e-4f), 2.0f);
    }
}

// ---------------------------------------------------------------------------
// K5: bx = xcat_g @ BxT^T, scaled by dtm.  Per g: M=16384, N=128, K=256.
__global__ __launch_bounds__(256) void k_bx_mfma(
    const ushort* __restrict__ xcat, const ushort* __restrict__ BxT,
    const float* __restrict__ dtm_,
    float* __restrict__ br, float* __restrict__ bi)
{
    __shared__ ushort lA[4096], lB[4096];
    int g = blockIdx.z;
    int bm = blockIdx.y * 128;
    int tid = threadIdx.x, wave = tid >> 6, lane = tid & 63;
    int row0 = wave*32 + (lane >> 2), col0 = (lane & 3) * 8;
    int r = lane & 15, h = lane >> 4;
    int wm = (wave & 1) * 64, wn = (wave >> 1) * 64;
    f32x4 acc[4][4] = {};
    mfma_core<256, 2048, 256>(xcat + (size_t)(bm + row0)*2048 + g*256 + col0,
                              BxT + (size_t)row0*256 + col0,
                              lA, lB, wave, lane, acc);
    #pragma unroll
    for (int i = 0; i < 4; i++) {
        int mb = bm + wm + i*16 + h*4;
        #pragma unroll
        for (int j = 0; j < 4; j++) {
            int n = wn + j*16 + r;
            #pragma unroll
            for (int t2 = 0; t2 < 4; t2++) {
                int m = mb + t2;
                float v = acc[i][j][t2] * dtm_[(size_t)m*8 + g];
                if (n < 64) br[(size_t)m*512 + g*64 + n]      = v;
                else        bi[(size_t)m*512 + g*64 + n - 64] = v;
            }
        }
    }
}

// ---------------------------------------------------------------------------
// K6: chunked scan, chunk = 64 steps (renorm fires after chunks with c%4==3).
// a computed on the fly from dtm/dtp + per-thread constants.
__global__ __launch_bounds__(256) void k_scan1(
    const float* __restrict__ br, const float* __restrict__ bi,
    const float* __restrict__ dtm_, const float* __restrict__ dtp_,
    const float* __restrict__ spl_t, const float* __restrict__ aph,
    float* __restrict__ Sar, float* __restrict__ Sai,
    float* __restrict__ Sbr, float* __restrict__ Sbi)
{
    int blk = blockIdx.x;                  // 512 = b(4) * c(64) * half(2)
    int half = blk & 1, c = (blk >> 1) & 63, b = blk >> 7;
    int t = half*256 + threadIdx.x;
    int g = t >> 6;
    float spl = spl_t[t], ap = aph[t];
    int row0 = b*SS + c*64;
    size_t idx = (size_t)row0 * 512 + t;
    const float* dtmp = dtm_ + (size_t)row0*8 + g;
    const float* dtpp = dtp_ + (size_t)row0*8 + g;
    float Ar = 1.f, Ai = 0.f, Br = 0.f, Bi = 0.f;
    for (int s0 = 0; s0 < 64; s0 += 4) {
        float vm[4], vp[4], wr[4], wi[4];
        #pragma unroll
        for (int u = 0; u < 4; u++) {
            vm[u] = dtmp[(s0+u)*8]; vp[u] = dtpp[(s0+u)*8];
            wr[u] = br[idx + (size_t)(s0+u)*512];
            wi[u] = bi[idx + (size_t)(s0+u)*512];
        }
        #pragma unroll
        for (int u = 0; u < 4; u++) {
            float am = expf(-vm[u]*spl);
            float sa, ca; sincosf(vp[u]*ap, &sa, &ca);
            float arv = am*ca, aiv = am*sa;
            float nBr = arv*Br - aiv*Bi + wr[u];
            float nBi = arv*Bi + aiv*Br + wi[u];
            float nAr = arv*Ar - aiv*Ai;
            float nAi = arv*Ai + aiv*Ar;
            Br = nBr; Bi = nBi; Ar = nAr; Ai = nAi;
        }
    }
    size_t o = ((size_t)(b*64 + c))*512 + t;
    Sar[o] = Ar; Sai[o] = Ai; Sbr[o] = Br; Sbi[o] = Bi;
}

__global__ __launch_bounds__(256) void k_scan2(
    const float* __restrict__ Sar, const float* __restrict__ Sai,
    const float* __restrict__ Sbr, const float* __restrict__ Sbi,
    float* __restrict__ hinr, float* __restrict__ hini)
{
    int blk = blockIdx.x;                  // 8 = b(4) * half(2)
    int half = blk & 1, b = blk >> 1;
    int t = half*256 + threadIdx.x;
    float hr = 0.f, hi = 0.f;
    for (int c = 0; c < 64; c++) {
        size_t o = ((size_t)(b*64 + c))*512 + t;
        hinr[o] = hr; hini[o] = hi;
        float nr = Sar[o]*hr - Sai[o]*hi + Sbr[o];
        float ni = Sar[o]*hi + Sai[o]*hr + Sbi[o];
        if ((c & 3) == 3) {
            float hn = sqrtf(nr*nr + ni*ni + 1e-8f);
            float sc = fminf(hn, 100.0f) / hn;
            nr *= sc; ni *= sc;
        }
        hr = nr; hi = ni;
    }
}

// scan3: recompute states; write H as bf16 A-matrix [row][1024] = [Hr(512)|Hi(512)].
__global__ __launch_bounds__(256) void k_scan3(
    const float* __restrict__ br, const float* __restrict__ bi,
    const float* __restrict__ dtm_, const float* __restrict__ dtp_,
    const float* __restrict__ spl_t, const float* __restrict__ aph,
    const float* __restrict__ hinr, const float* __restrict__ hini,
    ushort* __restrict__ Hbf)
{
    int blk = blockIdx.x;
    int half = blk & 1, c = (blk >> 1) & 63, b = blk >> 7;
    int t = half*256 + threadIdx.x;
    int g = t >> 6;
    float spl = spl_t[t], ap = aph[t];
    int row0 = b*SS + c*64;
    size_t idx = (size_t)row0 * 512 + t;
    const float* dtmp = dtm_ + (size_t)row0*8 + g;
    const float* dtpp = dtp_ + (size_t)row0*8 + g;
    size_t o = ((size_t)(b*64 + c))*512 + t;
    float hr = hinr[o], hi = hini[o];
    bool rch = ((c & 3) == 3);
    for (int s0 = 0; s0 < 64; s0 += 4) {
        float vm[4], vp[4], wr[4], wi[4];
        #pragma unroll
        for (int u = 0; u < 4; u++) {
            vm[u] = dtmp[(s0+u)*8]; vp[u] = dtpp[(s0+u)*8];
            wr[u] = br[idx + (size_t)(s0+u)*512];
            wi[u] = bi[idx + (size_t)(s0+u)*512];
        }
        #pragma unroll
        for (int u = 0; u < 4; u++) {
            float am = expf(-vm[u]*spl);
            float sa, ca; sincosf(vp[u]*ap, &sa, &ca);
            float arv = am*ca, aiv = am*sa;
            float nr = arv*hr - aiv*hi + wr[u];
            float ni = arv*hi + aiv*hr + wi[u];
            if (rch && (s0 + u == 63)) {
                float hn = sqrtf(nr*nr + ni*ni + 1e-8f);
                float sc = fminf(hn, 100.0f) / hn;
                nr *= sc; ni *= sc;
            }
            size_t rb = (size_t)(row0 + s0 + u) * 1024;
            Hbf[rb + t]       = f2b(nr);
            Hbf[rb + 512 + t] = f2b(ni);
            hr = nr; hi = ni;
        }
    }
}

// ---------------------------------------------------------------------------
// K7: out = x + res*ssm*(H @ P).  M=16384, N=2048, K=1024.
__global__ __launch_bounds__(256) void k_out_mfma(
    const ushort* __restrict__ A, const ushort* __restrict__ B,
    const float* __restrict__ ssm,
    const float* __restrict__ xr0, const float* __restrict__ xi0,
    const float* __restrict__ res_scale, float* __restrict__ out)
{
    __shared__ ushort lA[4096], lB[4096];
    int bm = blockIdx.y * 128, bn = blockIdx.x * 128;
    int tid = threadIdx.x, wave = tid >> 6, lane = tid & 63;
    int row0 = wave*32 + (lane >> 2), col0 = (lane & 3) * 8;
    int r = lane & 15, h = lane >> 4;
    int wm = (wave & 1) * 64, wn = (wave >> 1) * 64;
    f32x4 acc[4][4] = {};
    mfma_core<1024, 1024, 1024>(A + (size_t)(bm + row0)*1024 + col0,
                                B + (size_t)(bn + row0)*1024 + col0,
                                lA, lB, wave, lane, acc);
    float rs = res_scale[0];
    bool isReal = (bn < 1024);
    #pragma unroll
    for (int i = 0; i < 4; i++) {
        int mb = bm + wm + i*16 + h*4;
        #pragma unroll
        for (int j = 0; j < 4; j++) {
            int n = bn + wn + j*16 + r;
            int e = n & 1023;
            float sc = ssm[e] * rs;
            #pragma unroll
            for (int t2 = 0; t2 < 4; t2++) {
                size_t p = (size_t)(mb + t2)*DD + e;
                if (isReal) out[2*p]     = xr0[p] + acc[i][j][t2]*sc;
                else        out[2*p + 1] = xi0[p] + acc[i][j][t2]*sc;
            }
        }
    }
}

// ---------------------------------------------------------------------------
extern "C" void kernel_launch(void* const* d_in, const int* in_sizes, int n_in,
                              void* d_out, int out_size, void* d_ws, size_t ws_size,
                              hipStream_t stream) {
    const float* x_r      = (const float*)d_in[0];
    const float* x_i      = (const float*)d_in[1];
    const float* norm_w   = (const float*)d_in[2];
    const float* sg_theta = (const float*)d_in[3];
    const float* sg_Wg    = (const float*)d_in[4];
    const float* sg_bg    = (const float*)d_in[5];
    const float* conv_w   = (const float*)d_in[6];
    const float* conv_b   = (const float*)d_in[7];
    const float* log_A    = (const float*)d_in[8];
    const float* A_phase  = (const float*)d_in[9];
    const float* B_Wr     = (const float*)d_in[10];
    const float* B_Wi     = (const float*)d_in[11];
    const float* C_Wr     = (const float*)d_in[12];
    const float* C_Wi     = (const float*)d_in[13];
    const float* dt_W     = (const float*)d_in[14];
    const float* dt_b     = (const float*)d_in[15];
    const float* out_Wr   = (const float*)d_in[16];
    const float* out_Wi   = (const float*)d_in[17];
    const float* act_thr  = (const float*)d_in[18];
    const float* ssm_s    = (const float*)d_in[19];
    const float* res_s    = (const float*)d_in[20];
    float* out = (float*)d_out;
    float* ws  = (float*)d_ws;

    float*  A     = ws;                       // rotated xr (f32)
    float*  Bv    = ws + BSD;                 // rotated xi (f32)
    float*  gateC = ws + 2*BSD;               // gate (f32)
    ushort* xcat  = (ushort*)(ws + 3*BSD);    // [16384][2048] bf16
    float*  br    = ws + 4*BSD;               // BSGN
    float*  bi    = ws + 4*BSD + BSGN;        // BSGN
    ushort* Hbf   = (ushort*)(ws + 4*BSD + 2*BSGN);  // [16384][1024] bf16 (BSGN slots)
    float*  sm    = ws + 4*BSD + 3*BSGN;      // small region
    float*  dtm   = sm;                       // 131072
    float*  dtp   = sm + 131072;
    float*  Sar   = sm + 2*131072;
    float*  Sai   = sm + 3*131072;
    float*  Sbr   = sm + 4*131072;
    float*  Sbi   = sm + 5*131072;
    float*  hinr  = sm + 6*131072;
    float*  hini  = sm + 7*131072;
    float*  spl   = sm + 8*131072;            // 512
    ushort* WgT   = (ushort*)(sm + 8*131072 + 512);      // 1048576 ushorts (524288 slots)
    ushort* BxT   = (ushort*)(sm + 8*131072 + 512 + 524288);   // 32768 ushorts (16384)
    ushort* A3    = BxT + 32768;                               // 32768 ushorts
    ushort* WoP   = A3 + 32768;                                // 2097152 ushorts
    ushort* Bbig  = WoP + 2097152;                             // 2097152 ushorts
    ushort* magbf = (ushort*)br;              // 32MB, dead before k_bx writes br

    k_prep<<<2048, 256, 0, stream>>>(sg_Wg, B_Wr, B_Wi, C_Wr, C_Wi, out_Wr, out_Wi,
                                     log_A, WgT, BxT, A3, WoP, spl);
    k_pgemm<<<dim3(8, 1, 8), 256, 0, stream>>>(A3, WoP, Bbig);
    k_norm<<<BS, 256, 0, stream>>>(x_r, x_i, norm_w, A, Bv, magbf);
    k_gate_mfma<<<dim3(8, 128), 256, 0, stream>>>(magbf, WgT, sg_bg, gateC);
    k_rotate<<<4096, 256, 0, stream>>>(A, Bv, gateC, sg_theta);
    k_convdt<<<BS, 256, 0, stream>>>(A, Bv, conv_w, conv_b, act_thr, dt_W, dt_b,
                                     xcat, dtm, dtp);
    k_bx_mfma<<<dim3(1, 128, 8), 256, 0, stream>>>(xcat, BxT, dtm, br, bi);
    k_scan1<<<512, 256, 0, stream>>>(br, bi, dtm, dtp, spl, A_phase, Sar, Sai, Sbr, Sbi);
    k_scan2<<<8, 256, 0, stream>>>(Sar, Sai, Sbr, Sbi, hinr, hini);
    k_scan3<<<512, 256, 0, stream>>>(br, bi, dtm, dtp, spl, A_phase, hinr, hini, Hbf);
    k_out_mfma<<<dim3(16, 128), 256, 0, stream>>>(Hbf, Bbig, ssm_s, x_r, x_i, res_s, out);
}

// Round 6
// 478.621 us; speedup vs baseline: 15.1588x; 1.3664x over previous
//
#include <hip/hip_runtime.h>
#include <hip/hip_bf16.h>
#include <math.h>

// Problem constants
#define BB 4
#define SS 4096
#define DD 1024
#define GG 8
#define NN 64
#define GDIM 128
#define BS (BB*SS)                    // 16384 rows
static const size_t BSD  = (size_t)BS * DD;      // 16,777,216
static const size_t BSGN = (size_t)BS * GG * NN; // 8,388,608

typedef __attribute__((ext_vector_type(8))) short bf16x8;
typedef __attribute__((ext_vector_type(4))) float f32x4;

__device__ inline ushort f2b(float x) {
    __hip_bfloat16 h = __float2bfloat16(x);
    return *reinterpret_cast<ushort*>(&h);
}

#define GL16(gp, lp) __builtin_amdgcn_global_load_lds( \
    (const __attribute__((address_space(1))) void*)(gp), \
    (__attribute__((address_space(3))) void*)(lp), 16, 0, 0)

// ---------------------------------------------------------------------------
// MFMA GEMM core (m97 structure, PROVEN replay-safe in rounds 2-3):
// 128x128 tile, 4 waves, BK=32, single LDS buffer, __syncthreads fences
// (full vmcnt drain at the barrier — correct by construction).
// A [M][LDA] bf16 row-major (gA pre-offset to tile+lane), B^T [N][LDB].
template<int KD, int LDA, int LDB>
__device__ __forceinline__ void mfma_core(
    const ushort* __restrict__ gA, const ushort* __restrict__ gB,
    ushort* lA, ushort* lB, int wave, int lane, f32x4 (&acc)[4][4])
{
    int r = lane & 15, h = lane >> 4;
    int wm = (wave & 1) * 64, wn = (wave >> 1) * 64;
    ushort* lA0 = lA + wave * 1024;
    ushort* lB0 = lB + wave * 1024;
    for (int k0 = 0; k0 < KD; k0 += 32) {
        __syncthreads();
        GL16(gA + k0,            lA0);
        GL16(gA + k0 + 16*LDA,   lA0 + 512);
        GL16(gB + k0,            lB0);
        GL16(gB + k0 + 16*LDB,   lB0 + 512);
        __syncthreads();
        bf16x8 af[4], bfv[4];
        #pragma unroll
        for (int i = 0; i < 4; i++) af[i]  = *(const bf16x8*)&lA[(wm + i*16 + r)*32 + h*8];
        #pragma unroll
        for (int j = 0; j < 4; j++) bfv[j] = *(const bf16x8*)&lB[(wn + j*16 + r)*32 + h*8];
        #pragma unroll
        for (int i = 0; i < 4; i++)
            #pragma unroll
            for (int j = 0; j < 4; j++)
                acc[i][j] = __builtin_amdgcn_mfma_f32_16x16x32_bf16(af[i], bfv[j], acc[i][j], 0, 0, 0);
    }
}

// ---------------------------------------------------------------------------
// K0: prep.  WgT = bf16(Wg);  BxT [128][256]; A3 [128][256]; WoP [1024][2048];
// spl = softplus(logA); ctab/stab = cos/sin(theta) expanded to 1024.
__global__ __launch_bounds__(256) void k_prep(
    const float* __restrict__ Wg, const float* __restrict__ BWr, const float* __restrict__ BWi,
    const float* __restrict__ CWr, const float* __restrict__ CWi,
    const float* __restrict__ Wor, const float* __restrict__ Woi,
    const float* __restrict__ logA, const float* __restrict__ theta,
    ushort* __restrict__ WgT, ushort* __restrict__ BxT, ushort* __restrict__ A3,
    ushort* __restrict__ WoP, float* __restrict__ spl,
    float* __restrict__ ctab, float* __restrict__ stab)
{
    const int S1 = 1048576;           // WgT
    const int S2 = S1 + 32768;        // BxT
    const int S3 = S2 + 32768;        // A3
    const int S4 = S3 + 2097152;      // WoP
    const int S5 = S4 + 512;          // spl
    const int S6 = S5 + 1024;         // ctab
    const int S7 = S6 + 1024;         // stab
    for (int idx = blockIdx.x * 256 + threadIdx.x; idx < S7; idx += gridDim.x * 256) {
        if (idx < S1) {
            WgT[idx] = f2b(Wg[idx]);
        } else if (idx < S2) {
            int j = idx - S1, n = j >> 8, kk = j & 255;
            float v;
            if (n < 64) v = (kk < 128) ? BWr[n*128 + kk] : -BWi[n*128 + (kk-128)];
            else { int n2 = n - 64; v = (kk < 128) ? BWi[n2*128 + kk] : BWr[n2*128 + (kk-128)]; }
            BxT[j] = f2b(v);
        } else if (idx < S3) {
            int j = idx - S2, m = j >> 8, kk = j & 255;
            float v;
            if (m < 64) v = (kk < 128) ? CWr[kk*64 + m] : -CWi[(kk-128)*64 + m];
            else { int n2 = m - 64; v = (kk < 128) ? CWi[kk*64 + n2] : CWr[(kk-128)*64 + n2]; }
            A3[j] = f2b(v);
        } else if (idx < S4) {
            int j = idx - S3, e = j >> 11, c = j & 2047;
            int g = c >> 8, kk = c & 255;
            float v = (kk < 128) ? Wor[(size_t)e*1024 + g*128 + kk]
                                 : Woi[(size_t)e*1024 + g*128 + (kk-128)];
            WoP[j] = f2b(v);
        } else if (idx < S5) {
            int j = idx - S4;
            spl[j] = log1pf(expf(logA[j]));
        } else if (idx < S6) {
            int j = idx - S5;
            ctab[j] = cosf(theta[j >> 3]);
        } else {
            int j = idx - S6;
            stab[j] = sinf(theta[j >> 3]);
        }
    }
}

// ---------------------------------------------------------------------------
// K0b: P = C-combined-with-Wo.  Per g: [Pr;Pi](128x1024) = A3(128x256) @ WoP_g^T.
__global__ __launch_bounds__(256) void k_pgemm(
    const ushort* __restrict__ A3, const ushort* __restrict__ WoP,
    ushort* __restrict__ Bbig)
{
    __shared__ ushort lA[4096], lB[4096];
    int g = blockIdx.z;
    int bn = blockIdx.x * 128;
    int tid = threadIdx.x, wave = tid >> 6, lane = tid & 63;
    int row0 = wave*32 + (lane >> 2), col0 = (lane & 3) * 8;
    int r = lane & 15, h = lane >> 4;
    int wm = (wave & 1) * 64, wn = (wave >> 1) * 64;
    f32x4 acc[4][4] = {};
    mfma_core<256, 256, 2048>(A3 + (size_t)row0*256 + col0,
                              WoP + (size_t)(bn + row0)*2048 + g*256 + col0,
                              lA, lB, wave, lane, acc);
    #pragma unroll
    for (int i = 0; i < 4; i++) {
        int mb = wm + i*16 + h*4;
        #pragma unroll
        for (int j = 0; j < 4; j++) {
            int e = bn + wn + j*16 + r;
            #pragma unroll
            for (int t2 = 0; t2 < 4; t2++) {
                int m = mb + t2;
                float v = acc[i][j][t2];
                if (m < 64) {
                    int col = g*64 + m;
                    Bbig[(size_t)e*1024 + col] = f2b(v);
                    Bbig[(size_t)(1024 + e)*1024 + 512 + col] = f2b(v);
                } else {
                    int col = g*64 + (m - 64);
                    Bbig[(size_t)e*1024 + 512 + col] = f2b(-v);
                    Bbig[(size_t)(1024 + e)*1024 + col] = f2b(v);
                }
            }
        }
    }
}

// ---------------------------------------------------------------------------
// K1: complex RMSNorm stats: mag (bf16) + inv (f32 per row).
__global__ __launch_bounds__(256) void k_norm(
    const float* __restrict__ xr_in, const float* __restrict__ xi_in,
    const float* __restrict__ norm_w,
    ushort* __restrict__ mag_o, float* __restrict__ inv_o)
{
    int row = blockIdx.x;
    int tid = threadIdx.x;
    size_t base = (size_t)row * DD;
    float4 vr = ((const float4*)(xr_in + base))[tid];
    float4 vi = ((const float4*)(xi_in + base))[tid];
    float ss = vr.x*vr.x + vr.y*vr.y + vr.z*vr.z + vr.w*vr.w
             + vi.x*vi.x + vi.y*vi.y + vi.z*vi.z + vi.w*vi.w;
    #pragma unroll
    for (int off = 32; off >= 1; off >>= 1) ss += __shfl_down(ss, off);
    __shared__ float ws4[4];
    if ((tid & 63) == 0) ws4[tid >> 6] = ss;
    __syncthreads();
    float tot = ws4[0] + ws4[1] + ws4[2] + ws4[3];
    float inv = rsqrtf(tot * (1.0f / DD) + 1e-6f);
    float4 w = ((const float4*)norm_w)[tid];
    vr.x *= inv * w.x; vr.y *= inv * w.y; vr.z *= inv * w.z; vr.w *= inv * w.w;
    vi.x *= inv * w.x; vi.y *= inv * w.y; vi.z *= inv * w.z; vi.w *= inv * w.w;
    ushort4 mb;
    mb.x = f2b(sqrtf(vr.x*vr.x + vi.x*vi.x + 1e-8f));
    mb.y = f2b(sqrtf(vr.y*vr.y + vi.y*vi.y + 1e-8f));
    mb.z = f2b(sqrtf(vr.z*vr.z + vi.z*vi.z + 1e-8f));
    mb.w = f2b(sqrtf(vr.w*vr.w + vi.w*vi.w + 1e-8f));
    ((ushort4*)(mag_o + base))[tid] = mb;
    if (tid == 0) inv_o[row] = inv;
}

// ---------------------------------------------------------------------------
// K2: gate = sigmoid(mag @ Wg^T + bg).  M=16384, N=1024, K=1024.
__global__ __launch_bounds__(256) void k_gate_mfma(
    const ushort* __restrict__ A, const ushort* __restrict__ B,
    const float* __restrict__ bg, float* __restrict__ gate)
{
    __shared__ ushort lA[4096], lB[4096];
    int bm = blockIdx.y * 128, bn = blockIdx.x * 128;
    int tid = threadIdx.x, wave = tid >> 6, lane = tid & 63;
    int row0 = wave*32 + (lane >> 2), col0 = (lane & 3) * 8;
    int r = lane & 15, h = lane >> 4;
    int wm = (wave & 1) * 64, wn = (wave >> 1) * 64;
    f32x4 acc[4][4] = {};
    mfma_core<1024, 1024, 1024>(A + (size_t)(bm + row0)*1024 + col0,
                                B + (size_t)(bn + row0)*1024 + col0,
                                lA, lB, wave, lane, acc);
    #pragma unroll
    for (int i = 0; i < 4; i++) {
        int mb = bm + wm + i*16 + h*4;
        #pragma unroll
        for (int j = 0; j < 4; j++) {
            int n = bn + wn + j*16 + r;
            float bias = bg[n];
            #pragma unroll
            for (int t2 = 0; t2 < 4; t2++) {
                float v = acc[i][j][t2] + bias;
                gate[(size_t)(mb + t2)*DD + n] = 1.0f / (1.0f + expf(-v));
            }
        }
    }
}

// ---------------------------------------------------------------------------
// K3: fused rotate + depthwise conv (K=4) + activation + xcat(bf16) + dt.
// 16 s-rows per block, history taps in registers; normed x recomputed from
// raw x * inv * norm_w; trig from table.
__global__ __launch_bounds__(256) void k_rotconv(
    const float* __restrict__ xr_raw, const float* __restrict__ xi_raw,
    const float* __restrict__ inv_, const float* __restrict__ norm_w,
    const float* __restrict__ gate,
    const float* __restrict__ ctab, const float* __restrict__ stab,
    const float* __restrict__ cw, const float* __restrict__ cb,
    const float* __restrict__ act_thr,
    const float* __restrict__ dtW, const float* __restrict__ dtb,
    ushort* __restrict__ xcat, float* __restrict__ dtm_o, float* __restrict__ dtp_o)
{
    const int CH = 16;
    int row0 = blockIdx.x * CH;
    int s0 = row0 & (SS - 1);
    int t = threadIdx.x, d0 = t * 4;
    int g = d0 >> 7, dd = d0 & 127;
    float4 w4  = *(const float4*)&norm_w[d0];
    float4 ct4 = *(const float4*)&ctab[d0];
    float4 st4 = *(const float4*)&stab[d0];
    float cwv[4][16];
    float cb0[4], cb1[4];
    #pragma unroll
    for (int j = 0; j < 4; j++) {
        #pragma unroll
        for (int q = 0; q < 4; q++)
            *(float4*)&cwv[j][q*4] = *(const float4*)&cw[(size_t)(2*(d0+j))*8 + q*4];
        cb0[j] = cb[2*(d0+j)];
        cb1[j] = cb[2*(d0+j) + 1];
    }
    float4 dtw0a = *(const float4*)&dtW[dd];
    float4 dtw0b = *(const float4*)&dtW[128 + dd];
    float4 dtw1a = *(const float4*)&dtW[256 + dd];
    float4 dtw1b = *(const float4*)&dtW[384 + dd];
    float ea  = expf(act_thr[0]);
    float db0 = dtb[0], db1 = dtb[1];

    float p1r[4] = {}, p1i[4] = {}, p2r[4] = {}, p2i[4] = {}, p3r[4] = {}, p3i[4] = {};
    auto rotrow = [&](int rr, float (&orr)[4], float (&ori)[4]) {
        float4 a  = *(const float4*)&xr_raw[(size_t)rr*DD + d0];
        float4 bq = *(const float4*)&xi_raw[(size_t)rr*DD + d0];
        float4 gq = *(const float4*)&gate[(size_t)rr*DD + d0];
        float iv = inv_[rr];
        #pragma unroll
        for (int j = 0; j < 4; j++) {
            float ar = ((const float*)&a)[j]  * iv * ((const float*)&w4)[j];
            float ai = ((const float*)&bq)[j] * iv * ((const float*)&w4)[j];
            float c = ((const float*)&ct4)[j], s = ((const float*)&st4)[j];
            float gg = ((const float*)&gq)[j];
            orr[j] = gg * (ar*c - ai*s);
            ori[j] = gg * (ar*s + ai*c);
        }
    };
    if (s0 >= 1) rotrow(row0 - 1, p1r, p1i);
    if (s0 >= 2) rotrow(row0 - 2, p2r, p2i);
    if (s0 >= 3) rotrow(row0 - 3, p3r, p3i);

    for (int sl = 0; sl < CH; sl++) {
        int row = row0 + sl;
        float rr0[4], ri0[4];
        rotrow(row, rr0, ri0);
        float p0 = 0.f, p1 = 0.f;
        ushort4 ur, ui;
        #pragma unroll
        for (int j = 0; j < 4; j++) {
            float cr = cb0[j]
                + p3r[j]*cwv[j][0]  + p2r[j]*cwv[j][1]  + p1r[j]*cwv[j][2]  + rr0[j]*cwv[j][3]
                + p3i[j]*cwv[j][4]  + p2i[j]*cwv[j][5]  + p1i[j]*cwv[j][6]  + ri0[j]*cwv[j][7];
            float ci = cb1[j]
                + p3r[j]*cwv[j][8]  + p2r[j]*cwv[j][9]  + p1r[j]*cwv[j][10] + rr0[j]*cwv[j][11]
                + p3i[j]*cwv[j][12] + p2i[j]*cwv[j][13] + p1i[j]*cwv[j][14] + ri0[j]*cwv[j][15];
            float act = 1.0f - expf(-(cr*cr + ci*ci) * ea);
            cr *= act; ci *= act;
            ((ushort*)&ur)[j] = f2b(cr);
            ((ushort*)&ui)[j] = f2b(ci);
            p0 += cr * ((const float*)&dtw0a)[j] + ci * ((const float*)&dtw0b)[j];
            p1 += cr * ((const float*)&dtw1a)[j] + ci * ((const float*)&dtw1b)[j];
        }
        *(ushort4*)&xcat[(size_t)row*2048 + g*256 + dd]       = ur;
        *(ushort4*)&xcat[(size_t)row*2048 + g*256 + 128 + dd] = ui;
        #pragma unroll
        for (int off = 16; off >= 1; off >>= 1) {
            p0 += __shfl_down(p0, off, 32);
            p1 += __shfl_down(p1, off, 32);
        }
        if ((t & 31) == 0) {
            dtm_o[(size_t)row*8 + g] = fminf(fmaxf(expf(p0 + db0), 1e-4f), 2.0f);
            dtp_o[(size_t)row*8 + g] = fminf(fmaxf(expf(p1 + db1), 1e-4f), 2.0f);
        }
        #pragma unroll
        for (int j = 0; j < 4; j++) {
            p3r[j] = p2r[j]; p3i[j] = p2i[j];
            p2r[j] = p1r[j]; p2i[j] = p1i[j];
            p1r[j] = rr0[j]; p1i[j] = ri0[j];
        }
    }
}

// ---------------------------------------------------------------------------
// K5: bx = xcat_g @ BxT^T, scaled by dtm; f32 outputs (precision-critical:
// bf16 here pushed absmax to 0.14 in round 4).
__global__ __launch_bounds__(256) void k_bx_mfma(
    const ushort* __restrict__ xcat, const ushort* __restrict__ BxT,
    const float* __restrict__ dtm_,
    float* __restrict__ br, float* __restrict__ bi)
{
    __shared__ ushort lA[4096], lB[4096];
    int g = blockIdx.z;
    int bm = blockIdx.y * 128;
    int tid = threadIdx.x, wave = tid >> 6, lane = tid & 63;
    int row0 = wave*32 + (lane >> 2), col0 = (lane & 3) * 8;
    int r = lane & 15, h = lane >> 4;
    int wm = (wave & 1) * 64, wn = (wave >> 1) * 64;
    f32x4 acc[4][4] = {};
    mfma_core<256, 2048, 256>(xcat + (size_t)(bm + row0)*2048 + g*256 + col0,
                              BxT + (size_t)row0*256 + col0,
                              lA, lB, wave, lane, acc);
    #pragma unroll
    for (int i = 0; i < 4; i++) {
        int mb = bm + wm + i*16 + h*4;
        #pragma unroll
        for (int j = 0; j < 4; j++) {
            int n = wn + j*16 + r;
            #pragma unroll
            for (int t2 = 0; t2 < 4; t2++) {
                int m = mb + t2;
                float v = acc[i][j][t2] * dtm_[(size_t)m*8 + g];
                if (n < 64) br[(size_t)m*512 + g*64 + n]      = v;
                else        bi[(size_t)m*512 + g*64 + n - 64] = v;
            }
        }
    }
}

// ---------------------------------------------------------------------------
// K6: chunked scan, chunk = 64 steps (renorm fires after chunks with c%4==3).
// a computed on the fly from dtm/dtp + per-thread constants.
__global__ __launch_bounds__(256) void k_scan1(
    const float* __restrict__ br, const float* __restrict__ bi,
    const float* __restrict__ dtm_, const float* __restrict__ dtp_,
    const float* __restrict__ spl_t, const float* __restrict__ aph,
    float* __restrict__ Sar, float* __restrict__ Sai,
    float* __restrict__ Sbr, float* __restrict__ Sbi)
{
    int blk = blockIdx.x;                  // 512 = b(4) * c(64) * half(2)
    int half = blk & 1, c = (blk >> 1) & 63, b = blk >> 7;
    int t = half*256 + threadIdx.x;
    int g = t >> 6;
    float spl = spl_t[t], ap = aph[t];
    int row0 = b*SS + c*64;
    size_t idx = (size_t)row0 * 512 + t;
    const float* dtmp = dtm_ + (size_t)row0*8 + g;
    const float* dtpp = dtp_ + (size_t)row0*8 + g;
    float Ar = 1.f, Ai = 0.f, Br = 0.f, Bi = 0.f;
    for (int s0 = 0; s0 < 64; s0 += 4) {
        float vm[4], vp[4], wr[4], wi[4];
        #pragma unroll
        for (int u = 0; u < 4; u++) {
            vm[u] = dtmp[(s0+u)*8]; vp[u] = dtpp[(s0+u)*8];
            wr[u] = br[idx + (size_t)(s0+u)*512];
            wi[u] = bi[idx + (size_t)(s0+u)*512];
        }
        #pragma unroll
        for (int u = 0; u < 4; u++) {
            float am = expf(-vm[u]*spl);
            float sa, ca; sincosf(vp[u]*ap, &sa, &ca);
            float arv = am*ca, aiv = am*sa;
            float nBr = arv*Br - aiv*Bi + wr[u];
            float nBi = arv*Bi + aiv*Br + wi[u];
            float nAr = arv*Ar - aiv*Ai;
            float nAi = arv*Ai + aiv*Ar;
            Br = nBr; Bi = nBi; Ar = nAr; Ai = nAi;
        }
    }
    size_t o = ((size_t)(b*64 + c))*512 + t;
    Sar[o] = Ar; Sai[o] = Ai; Sbr[o] = Br; Sbi[o] = Bi;
}

__global__ __launch_bounds__(256) void k_scan2(
    const float* __restrict__ Sar, const float* __restrict__ Sai,
    const float* __restrict__ Sbr, const float* __restrict__ Sbi,
    float* __restrict__ hinr, float* __restrict__ hini)
{
    int blk = blockIdx.x;                  // 8 = b(4) * half(2)
    int half = blk & 1, b = blk >> 1;
    int t = half*256 + threadIdx.x;
    float hr = 0.f, hi = 0.f;
    for (int c = 0; c < 64; c++) {
        size_t o = ((size_t)(b*64 + c))*512 + t;
        hinr[o] = hr; hini[o] = hi;
        float nr = Sar[o]*hr - Sai[o]*hi + Sbr[o];
        float ni = Sar[o]*hi + Sai[o]*hr + Sbi[o];
        if ((c & 3) == 3) {
            float hn = sqrtf(nr*nr + ni*ni + 1e-8f);
            float sc = fminf(hn, 100.0f) / hn;
            nr *= sc; ni *= sc;
        }
        hr = nr; hi = ni;
    }
}

// scan3: recompute states; write H as bf16 A-matrix [row][1024] = [Hr|Hi].
__global__ __launch_bounds__(256) void k_scan3(
    const float* __restrict__ br, const float* __restrict__ bi,
    const float* __restrict__ dtm_, const float* __restrict__ dtp_,
    const float* __restrict__ spl_t, const float* __restrict__ aph,
    const float* __restrict__ hinr, const float* __restrict__ hini,
    ushort* __restrict__ Hbf)
{
    int blk = blockIdx.x;
    int half = blk & 1, c = (blk >> 1) & 63, b = blk >> 7;
    int t = half*256 + threadIdx.x;
    int g = t >> 6;
    float spl = spl_t[t], ap = aph[t];
    int row0 = b*SS + c*64;
    size_t idx = (size_t)row0 * 512 + t;
    const float* dtmp = dtm_ + (size_t)row0*8 + g;
    const float* dtpp = dtp_ + (size_t)row0*8 + g;
    size_t o = ((size_t)(b*64 + c))*512 + t;
    float hr = hinr[o], hi = hini[o];
    bool rch = ((c & 3) == 3);
    for (int s0 = 0; s0 < 64; s0 += 4) {
        float vm[4], vp[4], wr[4], wi[4];
        #pragma unroll
        for (int u = 0; u < 4; u++) {
            vm[u] = dtmp[(s0+u)*8]; vp[u] = dtpp[(s0+u)*8];
            wr[u] = br[idx + (size_t)(s0+u)*512];
            wi[u] = bi[idx + (size_t)(s0+u)*512];
        }
        #pragma unroll
        for (int u = 0; u < 4; u++) {
            float am = expf(-vm[u]*spl);
            float sa, ca; sincosf(vp[u]*ap, &sa, &ca);
            float arv = am*ca, aiv = am*sa;
            float nr = arv*hr - aiv*hi + wr[u];
            float ni = arv*hi + aiv*hr + wi[u];
            if (rch && (s0 + u == 63)) {
                float hn = sqrtf(nr*nr + ni*ni + 1e-8f);
                float sc = fminf(hn, 100.0f) / hn;
                nr *= sc; ni *= sc;
            }
            size_t rb = (size_t)(row0 + s0 + u) * 1024;
            Hbf[rb + t]       = f2b(nr);
            Hbf[rb + 512 + t] = f2b(ni);
            hr = nr; hi = ni;
        }
    }
}

// ---------------------------------------------------------------------------
// K7: out = x + res*ssm*(H @ P).  M=16384, N=2048, K=1024.
__global__ __launch_bounds__(256) void k_out_mfma(
    const ushort* __restrict__ A, const ushort* __restrict__ B,
    const float* __restrict__ ssm,
    const float* __restrict__ xr0, const float* __restrict__ xi0,
    const float* __restrict__ res_scale, float* __restrict__ out)
{
    __shared__ ushort lA[4096], lB[4096];
    int bm = blockIdx.y * 128, bn = blockIdx.x * 128;
    int tid = threadIdx.x, wave = tid >> 6, lane = tid & 63;
    int row0 = wave*32 + (lane >> 2), col0 = (lane & 3) * 8;
    int r = lane & 15, h = lane >> 4;
    int wm = (wave & 1) * 64, wn = (wave >> 1) * 64;
    f32x4 acc[4][4] = {};
    mfma_core<1024, 1024, 1024>(A + (size_t)(bm + row0)*1024 + col0,
                                B + (size_t)(bn + row0)*1024 + col0,
                                lA, lB, wave, lane, acc);
    float rs = res_scale[0];
    bool isReal = (bn < 1024);
    #pragma unroll
    for (int i = 0; i < 4; i++) {
        int mb = bm + wm + i*16 + h*4;
        #pragma unroll
        for (int j = 0; j < 4; j++) {
            int n = bn + wn + j*16 + r;
            int e = n & 1023;
            float sc = ssm[e] * rs;
            #pragma unroll
            for (int t2 = 0; t2 < 4; t2++) {
                size_t p = (size_t)(mb + t2)*DD + e;
                if (isReal) out[2*p]     = xr0[p] + acc[i][j][t2]*sc;
                else        out[2*p + 1] = xi0[p] + acc[i][j][t2]*sc;
            }
        }
    }
}

// ---------------------------------------------------------------------------
extern "C" void kernel_launch(void* const* d_in, const int* in_sizes, int n_in,
                              void* d_out, int out_size, void* d_ws, size_t ws_size,
                              hipStream_t stream) {
    const float* x_r      = (const float*)d_in[0];
    const float* x_i      = (const float*)d_in[1];
    const float* norm_w   = (const float*)d_in[2];
    const float* sg_theta = (const float*)d_in[3];
    const float* sg_Wg    = (const float*)d_in[4];
    const float* sg_bg    = (const float*)d_in[5];
    const float* conv_w   = (const float*)d_in[6];
    const float* conv_b   = (const float*)d_in[7];
    const float* log_A    = (const float*)d_in[8];
    const float* A_phase  = (const float*)d_in[9];
    const float* B_Wr     = (const float*)d_in[10];
    const float* B_Wi     = (const float*)d_in[11];
    const float* C_Wr     = (const float*)d_in[12];
    const float* C_Wi     = (const float*)d_in[13];
    const float* dt_W     = (const float*)d_in[14];
    const float* dt_b     = (const float*)d_in[15];
    const float* out_Wr   = (const float*)d_in[16];
    const float* out_Wi   = (const float*)d_in[17];
    const float* act_thr  = (const float*)d_in[18];
    const float* ssm_s    = (const float*)d_in[19];
    const float* res_s    = (const float*)d_in[20];
    float* out = (float*)d_out;
    float* ws  = (float*)d_ws;

    float*  gate  = ws;                                  // BSD f32
    ushort* xcat  = (ushort*)(ws + BSD);                 // BS*2048 bf16 (BSD f32 slots)
    ushort* magbf = (ushort*)(ws + 2*BSD);               // BS*1024 bf16 (BSGN f32 slots)
    float*  br    = ws + 2*BSD + BSGN;                   // BSGN f32
    float*  bi    = ws + 2*BSD + 2*BSGN;                 // BSGN f32
    ushort* Hbf   = (ushort*)(ws + 2*BSD + 3*BSGN);      // BS*1024 bf16 (BSGN f32 slots)
    float*  sm    = ws + 2*BSD + 4*BSGN;
    float*  dtm   = sm;
    float*  dtp   = sm + 131072;
    float*  Sar   = sm + 2*131072;
    float*  Sai   = sm + 3*131072;
    float*  Sbr   = sm + 4*131072;
    float*  Sbi   = sm + 5*131072;
    float*  hinr  = sm + 6*131072;
    float*  hini  = sm + 7*131072;
    float*  inv   = sm + 8*131072;                       // 16384
    float*  spl   = inv + 16384;                         // 512
    float*  ctab  = spl + 512;                           // 1024
    float*  stab  = ctab + 1024;                         // 1024
    ushort* WgT   = (ushort*)(stab + 1024);              // 1048576
    ushort* BxT   = WgT + 1048576;                       // 32768
    ushort* A3    = BxT + 32768;                         // 32768
    ushort* WoP   = A3 + 32768;                          // 2097152
    ushort* Bbig  = WoP + 2097152;                       // 2097152

    k_prep<<<2048, 256, 0, stream>>>(sg_Wg, B_Wr, B_Wi, C_Wr, C_Wi, out_Wr, out_Wi,
                                     log_A, sg_theta, WgT, BxT, A3, WoP, spl, ctab, stab);
    k_pgemm<<<dim3(8, 1, 8), 256, 0, stream>>>(A3, WoP, Bbig);
    k_norm<<<BS, 256, 0, stream>>>(x_r, x_i, norm_w, magbf, inv);
    k_gate_mfma<<<dim3(8, 128), 256, 0, stream>>>(magbf, WgT, sg_bg, gate);
    k_rotconv<<<BS/16, 256, 0, stream>>>(x_r, x_i, inv, norm_w, gate, ctab, stab,
                                         conv_w, conv_b, act_thr, dt_W, dt_b,
                                         xcat, dtm, dtp);
    k_bx_mfma<<<dim3(1, 128, 8), 256, 0, stream>>>(xcat, BxT, dtm, br, bi);
    k_scan1<<<512, 256, 0, stream>>>(br, bi, dtm, dtp, spl, A_phase, Sar, Sai, Sbr, Sbi);
    k_scan2<<<8, 256, 0, stream>>>(Sar, Sai, Sbr, Sbi, hinr, hini);
    k_scan3<<<512, 256, 0, stream>>>(br, bi, dtm, dtp, spl, A_phase, hinr, hini, Hbf);
    k_out_mfma<<<dim3(16, 128), 256, 0, stream>>>(Hbf, Bbig, ssm_s, x_r, x_i, res_s, out);
}